// Round 6
// baseline (3054.354 us; speedup 1.0000x reference)
//
#include <hip/hip_runtime.h>
#include <hip/hip_bf16.h>

// StockFormer forward, MI355X. Shapes fixed by the reference:
// B=4, S=256, N=128, F=64, D=E=128, NH=4, HD=32, BN=512, M=BN*S=131072
// OUTPUT IS FLOAT32 (reference returns jnp.float32; harness binds d_out to it).
constexpr long SFV6_BUF = 512L * 256L * 128L;  // 16,777,216 f32 (64 MiB)

// ---------------------------------------------------------------------------
// z = xl_cat transposed to (bn,s,e) + positional encoding  (flat row = bn*256+s)
// ---------------------------------------------------------------------------
__global__ __launch_bounds__(256) void sfv6_build_z(const float* __restrict__ x,
                                                    float* __restrict__ z) {
  long i = (long)blockIdx.x * 256 + threadIdx.x;
  if (i >= SFV6_BUF) return;
  int e = (int)(i & 127);
  int s = (int)((i >> 7) & 255);
  int r = (int)(i >> 15);          // bn = b*128+n
  int b = r >> 7, n = r & 127;
  float val;
  if (e < 64) {
    val = x[(((long)b * 256 + s) * 128 + n) * 64 + e];
  } else {
    int f = e - 64;
    int t2 = s >> 1;
    float a0 = x[(((long)b * 256 + 2 * t2) * 128 + n) * 64 + f];
    float a1 = x[(((long)b * 256 + 2 * t2 + 1) * 128 + n) * 64 + f];
    val = 0.5f * (a0 + a1);
  }
  int ii = e >> 1;
  float dv = expf(-0.0719557945041855f * (float)(2 * ii));  // exp(2i*(-ln1e4/128))
  float ang = (float)s * dv;
  float pe = (e & 1) ? cosf(ang) : sinf(ang);   // precise versions (args up to 255 rad)
  z[i] = val + pe;
}

// ---------------------------------------------------------------------------
// linear: Y[M,128] = X[M,128] @ W[128,128]^T + b   (ACC: Y += result)
// 64x64 tile, two K-panels of 64, 256 threads, 4x4 micro-tile. LDS ~35 KB.
// Out-of-place only.
// ---------------------------------------------------------------------------
template <bool ACC>
__global__ __launch_bounds__(256) void sfv6_linear(const float* __restrict__ X,
                                                   const float* __restrict__ W,
                                                   const float* __restrict__ bias,
                                                   float* __restrict__ Y) {
  __shared__ float Xs[64 * 68];
  __shared__ float Ws[64 * 68];
  __shared__ float bs[64];
  const int t = threadIdx.x;
  const long row0 = (long)(blockIdx.x >> 1) * 64;
  const int col0 = (blockIdx.x & 1) * 64;
  if (t < 64) bs[t] = bias[col0 + t];
  const int r0 = (t >> 4) << 2;
  const int c0 = (t & 15) << 2;
  float acc[4][4] = {};
  for (int kp = 0; kp < 2; ++kp) {
    __syncthreads();
#pragma unroll
    for (int i = 0; i < 4; ++i) {
      int chunk = i * 256 + t;         // float4 slots [0,1024)
      int r = chunk >> 4;              // [0,64)
      int k4 = (chunk & 15) << 2;      // [0,64)
      float4 xv = *reinterpret_cast<const float4*>(X + (row0 + r) * 128 + kp * 64 + k4);
      float4 wv = *reinterpret_cast<const float4*>(W + (long)(col0 + r) * 128 + kp * 64 + k4);
      float* xd = &Xs[r * 68 + k4];
      xd[0] = xv.x; xd[1] = xv.y; xd[2] = xv.z; xd[3] = xv.w;
      float* wd = &Ws[r * 68 + k4];
      wd[0] = wv.x; wd[1] = wv.y; wd[2] = wv.z; wd[3] = wv.w;
    }
    __syncthreads();
#pragma unroll 8
    for (int k = 0; k < 64; ++k) {
      float xr[4], wr[4];
#pragma unroll
      for (int i = 0; i < 4; ++i) xr[i] = Xs[(r0 + i) * 68 + k];
#pragma unroll
      for (int j = 0; j < 4; ++j) wr[j] = Ws[(c0 + j) * 68 + k];
#pragma unroll
      for (int i = 0; i < 4; ++i)
#pragma unroll
        for (int j = 0; j < 4; ++j) acc[i][j] = fmaf(xr[i], wr[j], acc[i][j]);
    }
  }
#pragma unroll
  for (int i = 0; i < 4; ++i) {
    float* yp = Y + (row0 + r0 + i) * 128 + col0 + c0;
    float4 o;
    o.x = acc[i][0] + bs[c0 + 0];
    o.y = acc[i][1] + bs[c0 + 1];
    o.z = acc[i][2] + bs[c0 + 2];
    o.w = acc[i][3] + bs[c0 + 3];
    if (ACC) {
      float4 p = *reinterpret_cast<const float4*>(yp);
      o.x += p.x; o.y += p.y; o.z += p.z; o.w += p.w;
    }
    *reinterpret_cast<float4*>(yp) = o;
  }
}

// ---------------------------------------------------------------------------
// dilated conv (k=3, pad 2, dil 2) over xh_cat as 3 shifted GEMMs + ReLU.
// Builds haar input on the fly from x; writes y_h raw-.view() flat layout:
// flat row (b*256+sc)*128+n  ==  (b*128+(sc>>1))*256 + ((sc&1)<<7) + n.
// ---------------------------------------------------------------------------
__global__ __launch_bounds__(256) void sfv6_conv3(const float* __restrict__ x,
                                                  const float* __restrict__ cw,
                                                  const float* __restrict__ bias,
                                                  float* __restrict__ Yh) {
  __shared__ float Xs[68 * 68];
  __shared__ float Ws[64 * 68];
  __shared__ float bs[64];
  const int t = threadIdx.x;
  int bid = blockIdx.x;
  const int col0 = (bid & 1) * 64; bid >>= 1;
  const int s0 = (bid & 3) * 64;   bid >>= 2;
  const int bnc = bid;             // [0,512)
  const int b = bnc >> 7, n = bnc & 127;
  if (t < 64) bs[t] = bias[col0 + t];
  const int r0 = (t >> 4) << 2;
  const int c0 = (t & 15) << 2;
  float acc[4][4] = {};
  for (int kp = 0; kp < 2; ++kp) {
    __syncthreads();
#pragma unroll
    for (int i = 0; i < 5; ++i) {
      int chunk = i * 256 + t;
      if (chunk < 68 * 16) {
        int r = chunk >> 4;            // [0,68)
        int k4 = (chunk & 15) << 2;    // [0,64)
        int s = s0 - 2 + r;
        float4 v = make_float4(0.f, 0.f, 0.f, 0.f);
        if (s >= 0 && s < 256) {
          if (kp == 0) {
            v = *reinterpret_cast<const float4*>(x + (((long)b * 256 + s) * 128 + n) * 64 + k4);
          } else {
            int t2 = s >> 1;
            float4 a0 = *reinterpret_cast<const float4*>(x + (((long)b * 256 + 2 * t2) * 128 + n) * 64 + k4);
            float4 a1 = *reinterpret_cast<const float4*>(x + (((long)b * 256 + 2 * t2 + 1) * 128 + n) * 64 + k4);
            float sg = (s & 1) ? -0.5f : 0.5f;
            v.x = sg * (a0.x - a1.x); v.y = sg * (a0.y - a1.y);
            v.z = sg * (a0.z - a1.z); v.w = sg * (a0.w - a1.w);
          }
        }
        float* xd = &Xs[r * 68 + k4];
        xd[0] = v.x; xd[1] = v.y; xd[2] = v.z; xd[3] = v.w;
      }
    }
    for (int tap = 0; tap < 3; ++tap) {
      __syncthreads();
#pragma unroll
      for (int i = 0; i < 4; ++i) {
        int chunk = i * 256 + t;
        int r = chunk >> 4;            // out-channel within tile
        int k4 = (chunk & 15) << 2;    // ic within panel
        long base = ((long)(col0 + r) * 128 + kp * 64 + k4) * 3 + tap;
        float* wd = &Ws[r * 68 + k4];
        wd[0] = cw[base];
        wd[1] = cw[base + 3];
        wd[2] = cw[base + 6];
        wd[3] = cw[base + 9];
      }
      __syncthreads();
#pragma unroll 8
      for (int k = 0; k < 64; ++k) {
        float xr[4], wr[4];
#pragma unroll
        for (int i = 0; i < 4; ++i) xr[i] = Xs[(r0 + 2 * tap + i) * 68 + k];
#pragma unroll
        for (int j = 0; j < 4; ++j) wr[j] = Ws[(c0 + j) * 68 + k];
#pragma unroll
        for (int i = 0; i < 4; ++i)
#pragma unroll
          for (int j = 0; j < 4; ++j) acc[i][j] = fmaf(xr[i], wr[j], acc[i][j]);
      }
    }
  }
#pragma unroll
  for (int i = 0; i < 4; ++i) {
    int sc = s0 + r0 + i;
    int rp = b * 128 + (sc >> 1);
    int sp = ((sc & 1) << 7) + n;
    float* yp = Yh + ((long)rp * 256 + sp) * 128 + col0 + c0;
    float4 o;
    o.x = fmaxf(acc[i][0] + bs[c0 + 0], 0.f);
    o.y = fmaxf(acc[i][1] + bs[c0 + 1], 0.f);
    o.z = fmaxf(acc[i][2] + bs[c0 + 2], 0.f);
    o.w = fmaxf(acc[i][3] + bs[c0 + 3], 0.f);
    *reinterpret_cast<float4*>(yp) = o;
  }
}

// ---------------------------------------------------------------------------
// fused-projection MHA (no out-proj): block = (bn, head). Flash over 4 tiles
// of 64 K/V rows, K/V projected on the fly (wave-split). Q per-thread from
// global Wq (wave-uniform addresses). LDS ~51 KB. O must not alias inputs.
// ---------------------------------------------------------------------------
__global__ __launch_bounds__(256) void sfv6_fattn(const float* Qsrc,
                                                  const float* KVsrc,
                                                  const float* __restrict__ Win,
                                                  const float* __restrict__ bin,
                                                  float* __restrict__ O) {
  __shared__ float Wk[32 * 128], Wv[32 * 128];
  __shared__ float bk[32], bv[32];
  __shared__ float Ks[64 * 36], Vs[64 * 36];
  const int t = threadIdx.x;
  const int bn = blockIdx.x >> 2;
  const int h = blockIdx.x & 3;
#pragma unroll
  for (int i = 0; i < 4; ++i) {
    int c = i * 256 + t;            // float4 slots [0,1024)
    int r = c >> 5;                 // [0,32)
    int k4 = (c & 31) << 2;
    *reinterpret_cast<float4*>(&Wk[r * 128 + k4]) =
        *reinterpret_cast<const float4*>(Win + ((long)(128 + h * 32 + r)) * 128 + k4);
    *reinterpret_cast<float4*>(&Wv[r * 128 + k4]) =
        *reinterpret_cast<const float4*>(Win + ((long)(256 + h * 32 + r)) * 128 + k4);
  }
  if (t < 32) { bk[t] = bin[128 + h * 32 + t]; bv[t] = bin[256 + h * 32 + t]; }
  float q[32];
  {
    const float* qrow = Qsrc + ((long)bn * 256 + t) * 128;
    const float* Wq = Win + (long)h * 32 * 128;
    const float* bq = bin + h * 32;
#pragma unroll
    for (int j = 0; j < 32; ++j) q[j] = bq[j];
    for (int k = 0; k < 128; k += 4) {
      float4 z4 = *reinterpret_cast<const float4*>(qrow + k);
#pragma unroll
      for (int j = 0; j < 32; ++j) {
        float4 w4 = *reinterpret_cast<const float4*>(Wq + j * 128 + k);
        q[j] = fmaf(z4.x, w4.x, fmaf(z4.y, w4.y, fmaf(z4.z, w4.z, fmaf(z4.w, w4.w, q[j]))));
      }
    }
    const float scale = 0.17677669529663687f;  // 1/sqrt(32)
#pragma unroll
    for (int j = 0; j < 32; ++j) q[j] *= scale;
  }
  float m = -INFINITY, l = 0.f;
  float acc[32];
#pragma unroll
  for (int j = 0; j < 32; ++j) acc[j] = 0.f;
  for (int tile = 0; tile < 4; ++tile) {
    __syncthreads();   // Ks/Vs reusable; also orders Wk/Wv staging on tile 0
    {
      const int w = t >> 6, lane = t & 63;
      const float* src = KVsrc + ((long)bn * 256 + tile * 64 + lane) * 128;
      const float* Wl = (w < 2) ? Wk : Wv;
      const float* bl = (w < 2) ? bk : bv;
      const int j0 = (w & 1) * 16;
      float a[16];
#pragma unroll
      for (int j = 0; j < 16; ++j) a[j] = bl[j0 + j];
      for (int k = 0; k < 128; k += 4) {
        float4 z4 = *reinterpret_cast<const float4*>(src + k);
#pragma unroll
        for (int j = 0; j < 16; ++j) {
          float4 w4 = *reinterpret_cast<const float4*>(&Wl[(j0 + j) * 128 + k]);
          a[j] = fmaf(z4.x, w4.x, fmaf(z4.y, w4.y, fmaf(z4.z, w4.z, fmaf(z4.w, w4.w, a[j]))));
        }
      }
      float* dst = (w < 2) ? &Ks[lane * 36 + j0] : &Vs[lane * 36 + j0];
#pragma unroll
      for (int j = 0; j < 16; j += 4) {
        float4 v4; v4.x = a[j]; v4.y = a[j + 1]; v4.z = a[j + 2]; v4.w = a[j + 3];
        *reinterpret_cast<float4*>(dst + j) = v4;
      }
    }
    __syncthreads();
#pragma unroll 2
    for (int kk = 0; kk < 64; ++kk) {
      float s = 0.f;
#pragma unroll
      for (int j = 0; j < 32; j += 4) {
        float4 kv = *reinterpret_cast<const float4*>(&Ks[kk * 36 + j]);
        s = fmaf(q[j], kv.x, fmaf(q[j + 1], kv.y, fmaf(q[j + 2], kv.z, fmaf(q[j + 3], kv.w, s))));
      }
      float mn = fmaxf(m, s);
      float corr = __expf(m - mn);
      float p = __expf(s - mn);
      l = l * corr + p;
      m = mn;
#pragma unroll
      for (int j = 0; j < 32; j += 4) {
        float4 vv = *reinterpret_cast<const float4*>(&Vs[kk * 36 + j]);
        acc[j]     = fmaf(acc[j],     corr, p * vv.x);
        acc[j + 1] = fmaf(acc[j + 1], corr, p * vv.y);
        acc[j + 2] = fmaf(acc[j + 2], corr, p * vv.z);
        acc[j + 3] = fmaf(acc[j + 3], corr, p * vv.w);
      }
    }
  }
  float inv = 1.f / l;
  float* orow = O + ((long)bn * 256 + t) * 128 + h * 32;
#pragma unroll
  for (int j = 0; j < 32; j += 4) {
    float4 o;
    o.x = acc[j] * inv; o.y = acc[j + 1] * inv;
    o.z = acc[j + 2] * inv; o.w = acc[j + 3] * inv;
    *reinterpret_cast<float4*>(orow + j) = o;
  }
}

// ---------------------------------------------------------------------------
// heads: reg = X@rw^T+rb ; cla = softmax2(X@cw^T+cb). All reference reshapes
// are raw views => output flat index == row. FLOAT32 stores.
// ---------------------------------------------------------------------------
__global__ __launch_bounds__(256) void sfv6_heads(const float* __restrict__ X,
                                                  const float* __restrict__ rw,
                                                  const float* __restrict__ rb,
                                                  const float* __restrict__ cw,
                                                  const float* __restrict__ cb,
                                                  float* __restrict__ out,
                                                  long off_reg, long off_cla) {
  __shared__ float w0[128], w1[128], w2[128];
  const int t = threadIdx.x;
  if (t < 128) { w0[t] = rw[t]; w1[t] = cw[t]; w2[t] = cw[128 + t]; }
  __syncthreads();
  long row = (long)blockIdx.x * 256 + t;
  const float* xr = X + row * 128;
  float d0 = 0.f, d1 = 0.f, d2 = 0.f;
#pragma unroll 8
  for (int j = 0; j < 128; j += 4) {
    float4 v = *reinterpret_cast<const float4*>(xr + j);
    d0 = fmaf(v.x, w0[j], fmaf(v.y, w0[j + 1], fmaf(v.z, w0[j + 2], fmaf(v.w, w0[j + 3], d0))));
    d1 = fmaf(v.x, w1[j], fmaf(v.y, w1[j + 1], fmaf(v.z, w1[j + 2], fmaf(v.w, w1[j + 3], d1))));
    d2 = fmaf(v.x, w2[j], fmaf(v.y, w2[j + 1], fmaf(v.z, w2[j + 2], fmaf(v.w, w2[j + 3], d2))));
  }
  d0 += rb[0]; d1 += cb[0]; d2 += cb[1];
  float mx = fmaxf(d1, d2);
  float e1 = expf(d1 - mx), e2 = expf(d2 - mx);
  float inv = 1.f / (e1 + e2);
  out[off_reg + row] = d0;
  out[off_cla + row * 2] = e1 * inv;
  out[off_cla + row * 2 + 1] = e2 * inv;
}

// ---------------------------------------------------------------------------
extern "C" void kernel_launch(void* const* d_in, const int* in_sizes, int n_in,
                              void* d_out, int out_size, void* d_ws, size_t ws_size,
                              hipStream_t stream) {
  (void)in_sizes; (void)n_in; (void)out_size; (void)ws_size;
  const float* x       = (const float*)d_in[0];
  const float* ta_w_in = (const float*)d_in[2];
  const float* ta_b_in = (const float*)d_in[3];
  const float* ta_w_o  = (const float*)d_in[4];
  const float* ta_b_o  = (const float*)d_in[5];
  const float* conv_w  = (const float*)d_in[6];
  const float* conv_b  = (const float*)d_in[7];
  const float* pl_w    = (const float*)d_in[8];
  const float* pl_b    = (const float*)d_in[9];
  const float* ph_w    = (const float*)d_in[10];
  const float* ph_b    = (const float*)d_in[11];
  const float* as_w_in = (const float*)d_in[12];
  const float* as_b_in = (const float*)d_in[13];
  const float* as_w_o  = (const float*)d_in[14];
  const float* as_b_o  = (const float*)d_in[15];
  const float* ac_w_in = (const float*)d_in[16];
  const float* ac_b_in = (const float*)d_in[17];
  const float* ac_w_o  = (const float*)d_in[18];
  const float* ac_b_o  = (const float*)d_in[19];
  const float* rl_w    = (const float*)d_in[20];
  const float* rl_b    = (const float*)d_in[21];
  const float* cl_w    = (const float*)d_in[22];
  const float* cl_b    = (const float*)d_in[23];
  const float* rf_w    = (const float*)d_in[24];
  const float* rf_b    = (const float*)d_in[25];
  const float* cf_w    = (const float*)d_in[26];
  const float* cf_b    = (const float*)d_in[27];
  float* out = (float*)d_out;   // FLOAT32 output (reference returns f32)

  float* S1 = (float*)d_ws;            // 3 x 64 MiB = 192 MiB
  float* S2 = S1 + SFV6_BUF;
  float* S3 = S2 + SFV6_BUF;

  const int GB = (int)(SFV6_BUF / 256);
  const int GL = 4096;                 // (131072/64) * (128/64)
  dim3 blk(256);

  // ---- encoder ----
  sfv6_build_z<<<GB, blk, 0, stream>>>(x, S1);                               // S1 = z
  sfv6_fattn<<<2048, blk, 0, stream>>>(S1, S1, ta_w_in, ta_b_in, S2);        // S2 = enc attn (pre-proj)
  sfv6_linear<false><<<GL, blk, 0, stream>>>(S2, ta_w_o, ta_b_o, S3);        // S3 = y_l
  sfv6_conv3<<<4096, blk, 0, stream>>>(x, conv_w, conv_b, S1);               // S1 = y_h

  // ---- decoder projections + aux heads ----
  sfv6_linear<false><<<GL, blk, 0, stream>>>(S1, ph_w, ph_b, S2);            // S2 = k_h
  sfv6_linear<false><<<GL, blk, 0, stream>>>(S3, pl_w, pl_b, S1);            // S1 = q_l
  sfv6_linear<false><<<GL, blk, 0, stream>>>(S1, pl_w, pl_b, S3);            // S3 = y_l2
  sfv6_heads<<<512, blk, 0, stream>>>(S3, rl_w, rl_b, cl_w, cl_b, out,
                                      393216L, 524288L);                     // lreg, lcla

  // ---- cross attention (q = q_l, k/v = k_h) ----
  sfv6_fattn<<<2048, blk, 0, stream>>>(S1, S2, ac_w_in, ac_b_in, S3);        // S3 = cross attn
  sfv6_linear<false><<<GL, blk, 0, stream>>>(S3, ac_w_o, ac_b_o, S2);        // S2 = a_cross

  // ---- self attention (q/k/v = q_l) ----
  sfv6_fattn<<<2048, blk, 0, stream>>>(S1, S1, as_w_in, as_b_in, S3);        // S3 = self attn
  sfv6_linear<true><<<GL, blk, 0, stream>>>(S3, as_w_o, as_b_o, S2);         // S2 = fused

  sfv6_heads<<<512, blk, 0, stream>>>(S2, rf_w, rf_b, cf_w, cf_b, out,
                                      0L, 131072L);                          // reg, cla
}

// Round 7
// 1258.452 us; speedup vs baseline: 2.4271x; 2.4271x over previous
//
#include <hip/hip_runtime.h>
#include <hip/hip_bf16.h>

// StockFormer forward, MI355X — bf16 MFMA pipeline.
// B=4, S=256, N=128, F=64, D=E=128, NH=4, HD=32, BN=512, M=131072. Output f32.
typedef __attribute__((ext_vector_type(8))) short short8v;   // 8 bf16 (4 VGPR)
typedef __attribute__((ext_vector_type(4))) float f32x4;
typedef __hip_bfloat16 bh;

constexpr long SF_ELEMS = 131072L * 128;   // elements per ws slot (bf16 -> 32 MiB)
#define MFMA16(a, b, c) __builtin_amdgcn_mfma_f32_16x16x32_bf16((a), (b), (c), 0, 0, 0)

// ---------------------------------------------------------------------------
// weight convert: 8 f32 weight matrices -> one bf16 arena (229376 elements)
// layout: 0 ta_w_in | 49152 ta_w_o | 65536 pl | 81920 ph | 98304 ac_w_in |
//         147456 ac_w_o | 163840 as_w_in | 212992 as_w_o
// ---------------------------------------------------------------------------
__global__ __launch_bounds__(256) void sf_wcvt(const float* __restrict__ s0, const float* __restrict__ s1,
                                               const float* __restrict__ s2, const float* __restrict__ s3,
                                               const float* __restrict__ s4, const float* __restrict__ s5,
                                               const float* __restrict__ s6, const float* __restrict__ s7,
                                               bh* __restrict__ dst) {
  int i = blockIdx.x * 256 + threadIdx.x;
  float v;
  if      (i <  49152) v = s0[i];
  else if (i <  65536) v = s1[i - 49152];
  else if (i <  81920) v = s2[i - 65536];
  else if (i <  98304) v = s3[i - 81920];
  else if (i < 147456) v = s4[i - 98304];
  else if (i < 163840) v = s5[i - 147456];
  else if (i < 212992) v = s6[i - 163840];
  else if (i < 229376) v = s7[i - 212992];
  else return;
  dst[i] = __float2bfloat16(v);
}

// ---------------------------------------------------------------------------
// z = xl_cat transposed to (bn,s,e) + positional encoding, bf16 store
// ---------------------------------------------------------------------------
__global__ __launch_bounds__(256) void sf_build_z(const float* __restrict__ x,
                                                  bh* __restrict__ z) {
  long i = (long)blockIdx.x * 256 + threadIdx.x;
  if (i >= SF_ELEMS) return;
  int e = (int)(i & 127);
  int s = (int)((i >> 7) & 255);
  int r = (int)(i >> 15);
  int b = r >> 7, n = r & 127;
  float val;
  if (e < 64) {
    val = x[(((long)b * 256 + s) * 128 + n) * 64 + e];
  } else {
    int f = e - 64;
    int t2 = s >> 1;
    float a0 = x[(((long)b * 256 + 2 * t2) * 128 + n) * 64 + f];
    float a1 = x[(((long)b * 256 + 2 * t2 + 1) * 128 + n) * 64 + f];
    val = 0.5f * (a0 + a1);
  }
  int ii = e >> 1;
  float dv = expf(-0.0719557945041855f * (float)(2 * ii));
  float ang = (float)s * dv;
  float pe = (e & 1) ? cosf(ang) : sinf(ang);
  z[i] = __float2bfloat16(val + pe);
}

// ---------------------------------------------------------------------------
// MFMA linear: Y[M,128](bf16) = X[M,128](bf16) @ Wb[128,128](bf16)^T + bias(f32)
// block 256 thr = 4 waves x 32 rows; frags straight from global (W is L2-hot).
// ACC: Y = result + Prev (bf16).
// ---------------------------------------------------------------------------
template <bool ACC>
__global__ __launch_bounds__(256) void sf_lin(const bh* __restrict__ X,
                                              const bh* __restrict__ Wb,
                                              const float* __restrict__ bias,
                                              const bh* __restrict__ Prev,
                                              bh* __restrict__ Y) {
  const int t = threadIdx.x, lane = t & 63, w = t >> 6;
  const int lr = lane & 15, lg = lane >> 4;
  const long R0 = (long)blockIdx.x * 128 + w * 32;
  const f32x4 z4 = {0.f, 0.f, 0.f, 0.f};
  f32x4 acc[2][8];
#pragma unroll
  for (int m = 0; m < 2; ++m)
#pragma unroll
    for (int n = 0; n < 8; ++n) acc[m][n] = z4;
#pragma unroll
  for (int ks = 0; ks < 4; ++ks) {
    short8v a0 = *reinterpret_cast<const short8v*>(X + (R0 + lr) * 128 + ks * 32 + lg * 8);
    short8v a1 = *reinterpret_cast<const short8v*>(X + (R0 + 16 + lr) * 128 + ks * 32 + lg * 8);
#pragma unroll
    for (int n = 0; n < 8; ++n) {
      short8v b = *reinterpret_cast<const short8v*>(Wb + (long)(n * 16 + lr) * 128 + ks * 32 + lg * 8);
      acc[0][n] = MFMA16(a0, b, acc[0][n]);
      acc[1][n] = MFMA16(a1, b, acc[1][n]);
    }
  }
#pragma unroll
  for (int n = 0; n < 8; ++n) {
    float bv = bias[n * 16 + lr];
#pragma unroll
    for (int m = 0; m < 2; ++m)
#pragma unroll
      for (int r = 0; r < 4; ++r) {
        long idx = (R0 + m * 16 + 4 * lg + r) * 128 + n * 16 + lr;
        float v = acc[m][n][r] + bv;
        if (ACC) v += __bfloat162float(Prev[idx]);
        Y[idx] = __float2bfloat16(v);
      }
  }
}

// ---------------------------------------------------------------------------
// MFMA flash attention: block = (bn, head), 4 waves x 64 q-rows, kv-tiles of 64.
// S = mfma(Q-rowfrag, K-rowfrag); softmax on C-layout (lane owns 4 q-rows x 1 k-col,
// reduce via shfl_xor 1/2/4/8); P -> per-wave LDS tile -> a-frags; PV with
// Vt (transposed at staging). All LDS rows stride 72 bf16 (144B, 16B-aligned).
// ---------------------------------------------------------------------------
__global__ __launch_bounds__(256) void sf_attn(const bh* __restrict__ Q, const bh* __restrict__ K,
                                               const bh* __restrict__ V, bh* __restrict__ O) {
  __shared__ bh Ks[64][72];
  __shared__ bh Vt[32][72];
  __shared__ bh Pl[4][16][72];
  const int t = threadIdx.x, lane = t & 63, w = t >> 6;
  const int lr = lane & 15, lg = lane >> 4;
  const int bn = blockIdx.x >> 2, h = blockIdx.x & 3;
  const long R0 = (long)bn * 256;
  const int ch = h * 32;
  short8v aq[4];
#pragma unroll
  for (int mt = 0; mt < 4; ++mt)
    aq[mt] = *reinterpret_cast<const short8v*>(Q + (R0 + w * 64 + mt * 16 + lr) * 128 + ch + lg * 8);
  const f32x4 z4 = {0.f, 0.f, 0.f, 0.f};
  f32x4 Oacc[4][2];
  float ms[4][4], ls[4][4];
#pragma unroll
  for (int mt = 0; mt < 4; ++mt) {
    Oacc[mt][0] = z4; Oacc[mt][1] = z4;
#pragma unroll
    for (int r = 0; r < 4; ++r) { ms[mt][r] = -1e30f; ls[mt][r] = 0.f; }
  }
  const float scale = 0.17677669529663687f;  // 1/sqrt(32)
  for (int kt = 0; kt < 4; ++kt) {
    __syncthreads();                       // previous tile's reads done
    {
      const int kr = t >> 2, cg = (t & 3) * 8;
      short8v kv = *reinterpret_cast<const short8v*>(K + (R0 + kt * 64 + kr) * 128 + ch + cg);
      *reinterpret_cast<short8v*>(&Ks[kr][cg]) = kv;
      short8v vv = *reinterpret_cast<const short8v*>(V + (R0 + kt * 64 + kr) * 128 + ch + cg);
      const bh* vp = reinterpret_cast<const bh*>(&vv);
#pragma unroll
      for (int j = 0; j < 8; ++j) Vt[cg + j][kr] = vp[j];   // transpose V
    }
    __syncthreads();
    short8v bv[2][2];
#pragma unroll
    for (int dt = 0; dt < 2; ++dt)
#pragma unroll
      for (int ks = 0; ks < 2; ++ks)
        bv[dt][ks] = *reinterpret_cast<const short8v*>(&Vt[dt * 16 + lr][ks * 32 + lg * 8]);
#pragma unroll
    for (int mt = 0; mt < 4; ++mt) {
      f32x4 S[4];
#pragma unroll
      for (int nt = 0; nt < 4; ++nt) {
        short8v bk = *reinterpret_cast<const short8v*>(&Ks[nt * 16 + lr][lg * 8]);
        S[nt] = MFMA16(aq[mt], bk, z4);
      }
#pragma unroll
      for (int r = 0; r < 4; ++r) {
        float s0 = S[0][r] * scale, s1 = S[1][r] * scale;
        float s2 = S[2][r] * scale, s3 = S[3][r] * scale;
        float tm = fmaxf(fmaxf(s0, s1), fmaxf(s2, s3));
        tm = fmaxf(tm, __shfl_xor(tm, 1, 64));
        tm = fmaxf(tm, __shfl_xor(tm, 2, 64));
        tm = fmaxf(tm, __shfl_xor(tm, 4, 64));
        tm = fmaxf(tm, __shfl_xor(tm, 8, 64));
        float mold = ms[mt][r];
        float mnew = fmaxf(mold, tm);
        float corr = __expf(mold - mnew);
        float p0 = __expf(s0 - mnew), p1 = __expf(s1 - mnew);
        float p2 = __expf(s2 - mnew), p3 = __expf(s3 - mnew);
        bh* pr = &Pl[w][4 * lg + r][lr];
        pr[0]  = __float2bfloat16(p0);
        pr[16] = __float2bfloat16(p1);
        pr[32] = __float2bfloat16(p2);
        pr[48] = __float2bfloat16(p3);
        float rs = p0 + p1 + p2 + p3;
        rs += __shfl_xor(rs, 1, 64); rs += __shfl_xor(rs, 2, 64);
        rs += __shfl_xor(rs, 4, 64); rs += __shfl_xor(rs, 8, 64);
        ls[mt][r] = ls[mt][r] * corr + rs;
        ms[mt][r] = mnew;
        Oacc[mt][0][r] *= corr;
        Oacc[mt][1][r] *= corr;
      }
#pragma unroll
      for (int ks = 0; ks < 2; ++ks) {
        short8v ap = *reinterpret_cast<const short8v*>(&Pl[w][lr][ks * 32 + lg * 8]);
        Oacc[mt][0] = MFMA16(ap, bv[0][ks], Oacc[mt][0]);
        Oacc[mt][1] = MFMA16(ap, bv[1][ks], Oacc[mt][1]);
      }
    }
  }
#pragma unroll
  for (int mt = 0; mt < 4; ++mt)
#pragma unroll
    for (int r = 0; r < 4; ++r) {
      float inv = 1.f / ls[mt][r];
      long row = R0 + w * 64 + mt * 16 + 4 * lg + r;
      O[row * 128 + ch + lr]      = __float2bfloat16(Oacc[mt][0][r] * inv);
      O[row * 128 + ch + 16 + lr] = __float2bfloat16(Oacc[mt][1][r] * inv);
    }
}

// ---------------------------------------------------------------------------
// dilated conv (k=3 pad2 dil2) as 3 shifted GEMMs + ReLU; f32 math, bf16 out.
// ---------------------------------------------------------------------------
__global__ __launch_bounds__(256) void sf_conv3(const float* __restrict__ x,
                                                const float* __restrict__ cw,
                                                const float* __restrict__ bias,
                                                bh* __restrict__ Yh) {
  __shared__ float Xs[68 * 68];
  __shared__ float Ws[64 * 68];
  __shared__ float bs[64];
  const int t = threadIdx.x;
  int bid = blockIdx.x;
  const int col0 = (bid & 1) * 64; bid >>= 1;
  const int s0 = (bid & 3) * 64;   bid >>= 2;
  const int bnc = bid;
  const int b = bnc >> 7, n = bnc & 127;
  if (t < 64) bs[t] = bias[col0 + t];
  const int r0 = (t >> 4) << 2;
  const int c0 = (t & 15) << 2;
  float acc[4][4] = {};
  for (int kp = 0; kp < 2; ++kp) {
    __syncthreads();
#pragma unroll
    for (int i = 0; i < 5; ++i) {
      int chunk = i * 256 + t;
      if (chunk < 68 * 16) {
        int r = chunk >> 4;
        int k4 = (chunk & 15) << 2;
        int s = s0 - 2 + r;
        float4 v = make_float4(0.f, 0.f, 0.f, 0.f);
        if (s >= 0 && s < 256) {
          if (kp == 0) {
            v = *reinterpret_cast<const float4*>(x + (((long)b * 256 + s) * 128 + n) * 64 + k4);
          } else {
            int t2 = s >> 1;
            float4 a0 = *reinterpret_cast<const float4*>(x + (((long)b * 256 + 2 * t2) * 128 + n) * 64 + k4);
            float4 a1 = *reinterpret_cast<const float4*>(x + (((long)b * 256 + 2 * t2 + 1) * 128 + n) * 64 + k4);
            float sg = (s & 1) ? -0.5f : 0.5f;
            v.x = sg * (a0.x - a1.x); v.y = sg * (a0.y - a1.y);
            v.z = sg * (a0.z - a1.z); v.w = sg * (a0.w - a1.w);
          }
        }
        float* xd = &Xs[r * 68 + k4];
        xd[0] = v.x; xd[1] = v.y; xd[2] = v.z; xd[3] = v.w;
      }
    }
    for (int tap = 0; tap < 3; ++tap) {
      __syncthreads();
#pragma unroll
      for (int i = 0; i < 4; ++i) {
        int chunk = i * 256 + t;
        int r = chunk >> 4;
        int k4 = (chunk & 15) << 2;
        long base = ((long)(col0 + r) * 128 + kp * 64 + k4) * 3 + tap;
        float* wd = &Ws[r * 68 + k4];
        wd[0] = cw[base]; wd[1] = cw[base + 3]; wd[2] = cw[base + 6]; wd[3] = cw[base + 9];
      }
      __syncthreads();
#pragma unroll 8
      for (int k = 0; k < 64; ++k) {
        float xr[4], wr[4];
#pragma unroll
        for (int i = 0; i < 4; ++i) xr[i] = Xs[(r0 + 2 * tap + i) * 68 + k];
#pragma unroll
        for (int j = 0; j < 4; ++j) wr[j] = Ws[(c0 + j) * 68 + k];
#pragma unroll
        for (int i = 0; i < 4; ++i)
#pragma unroll
          for (int j = 0; j < 4; ++j) acc[i][j] = fmaf(xr[i], wr[j], acc[i][j]);
      }
    }
  }
#pragma unroll
  for (int i = 0; i < 4; ++i) {
    int sc = s0 + r0 + i;
    int rp = b * 128 + (sc >> 1);
    int sp = ((sc & 1) << 7) + n;
    bh* yp = Yh + ((long)rp * 256 + sp) * 128 + col0 + c0;
    yp[0] = __float2bfloat16(fmaxf(acc[i][0] + bs[c0 + 0], 0.f));
    yp[1] = __float2bfloat16(fmaxf(acc[i][1] + bs[c0 + 1], 0.f));
    yp[2] = __float2bfloat16(fmaxf(acc[i][2] + bs[c0 + 2], 0.f));
    yp[3] = __float2bfloat16(fmaxf(acc[i][3] + bs[c0 + 3], 0.f));
  }
}

// ---------------------------------------------------------------------------
// heads: reg = X@rw^T+rb ; cla = softmax2(X@cw^T+cb); bf16 in, f32 out (idx=row)
// ---------------------------------------------------------------------------
__global__ __launch_bounds__(256) void sf_heads(const bh* __restrict__ X,
                                                const float* __restrict__ rw,
                                                const float* __restrict__ rb,
                                                const float* __restrict__ cw,
                                                const float* __restrict__ cb,
                                                float* __restrict__ out,
                                                long off_reg, long off_cla) {
  __shared__ float w0[128], w1[128], w2[128];
  const int t = threadIdx.x;
  if (t < 128) { w0[t] = rw[t]; w1[t] = cw[t]; w2[t] = cw[128 + t]; }
  __syncthreads();
  long row = (long)blockIdx.x * 256 + t;
  const bh* xr = X + row * 128;
  float d0 = 0.f, d1 = 0.f, d2 = 0.f;
#pragma unroll 4
  for (int j = 0; j < 128; j += 8) {
    short8v v8 = *reinterpret_cast<const short8v*>(xr + j);
    const bh* vv = reinterpret_cast<const bh*>(&v8);
#pragma unroll
    for (int k = 0; k < 8; ++k) {
      float f = __bfloat162float(vv[k]);
      d0 = fmaf(f, w0[j + k], d0);
      d1 = fmaf(f, w1[j + k], d1);
      d2 = fmaf(f, w2[j + k], d2);
    }
  }
  d0 += rb[0]; d1 += cb[0]; d2 += cb[1];
  float mx = fmaxf(d1, d2);
  float e1 = expf(d1 - mx), e2 = expf(d2 - mx);
  float inv = 1.f / (e1 + e2);
  out[off_reg + row] = d0;
  out[off_cla + row * 2] = e1 * inv;
  out[off_cla + row * 2 + 1] = e2 * inv;
}

// ---------------------------------------------------------------------------
extern "C" void kernel_launch(void* const* d_in, const int* in_sizes, int n_in,
                              void* d_out, int out_size, void* d_ws, size_t ws_size,
                              hipStream_t stream) {
  (void)in_sizes; (void)n_in; (void)out_size; (void)ws_size;
  const float* x       = (const float*)d_in[0];
  const float* ta_w_in = (const float*)d_in[2];
  const float* ta_b_in = (const float*)d_in[3];
  const float* ta_w_o  = (const float*)d_in[4];
  const float* ta_b_o  = (const float*)d_in[5];
  const float* conv_w  = (const float*)d_in[6];
  const float* conv_b  = (const float*)d_in[7];
  const float* pl_w    = (const float*)d_in[8];
  const float* pl_b    = (const float*)d_in[9];
  const float* ph_w    = (const float*)d_in[10];
  const float* ph_b    = (const float*)d_in[11];
  const float* as_w_in = (const float*)d_in[12];
  const float* as_b_in = (const float*)d_in[13];
  const float* as_w_o  = (const float*)d_in[14];
  const float* as_b_o  = (const float*)d_in[15];
  const float* ac_w_in = (const float*)d_in[16];
  const float* ac_b_in = (const float*)d_in[17];
  const float* ac_w_o  = (const float*)d_in[18];
  const float* ac_b_o  = (const float*)d_in[19];
  const float* rl_w    = (const float*)d_in[20];
  const float* rl_b    = (const float*)d_in[21];
  const float* cl_w    = (const float*)d_in[22];
  const float* cl_b    = (const float*)d_in[23];
  const float* rf_w    = (const float*)d_in[24];
  const float* rf_b    = (const float*)d_in[25];
  const float* cf_w    = (const float*)d_in[26];
  const float* cf_b    = (const float*)d_in[27];
  float* out = (float*)d_out;

  bh* S0 = (bh*)d_ws;                 // 5 slots x 32 MiB + 0.5 MiB arena = 160.5 MiB
  bh* S1 = S0 + SF_ELEMS;
  bh* S2 = S1 + SF_ELEMS;
  bh* S3 = S2 + SF_ELEMS;
  bh* S4 = S3 + SF_ELEMS;
  bh* A  = S4 + SF_ELEMS;             // weight arena (229376 bf16)

  dim3 blk(256);
  const int GZ = (int)(SF_ELEMS / 256);
  const int GL = 1024;                // 131072 / 128

  sf_wcvt<<<896, blk, 0, stream>>>(ta_w_in, ta_w_o, pl_w, ph_w,
                                   ac_w_in, ac_w_o, as_w_in, as_w_o, A);

  // ---- encoder ----
  sf_build_z<<<GZ, blk, 0, stream>>>(x, S0);                                  // S0 = z
  sf_lin<false><<<GL, blk, 0, stream>>>(S0, A,          ta_b_in,       nullptr, S1); // Q
  sf_lin<false><<<GL, blk, 0, stream>>>(S0, A + 16384,  ta_b_in + 128, nullptr, S2); // K
  sf_lin<false><<<GL, blk, 0, stream>>>(S0, A + 32768,  ta_b_in + 256, nullptr, S3); // V
  sf_attn<<<2048, blk, 0, stream>>>(S1, S2, S3, S4);                          // S4 = enc attn
  sf_lin<false><<<GL, blk, 0, stream>>>(S4, A + 49152, ta_b_o, nullptr, S0);  // S0 = y_l
  sf_conv3<<<4096, blk, 0, stream>>>(x, conv_w, conv_b, S1);                  // S1 = y_h

  // ---- decoder projections + aux heads ----
  sf_lin<false><<<GL, blk, 0, stream>>>(S1, A + 81920, ph_b, nullptr, S2);    // S2 = k_h
  sf_lin<false><<<GL, blk, 0, stream>>>(S0, A + 65536, pl_b, nullptr, S3);    // S3 = q_l
  sf_lin<false><<<GL, blk, 0, stream>>>(S3, A + 65536, pl_b, nullptr, S4);    // S4 = y_l2
  sf_heads<<<512, blk, 0, stream>>>(S4, rl_w, rl_b, cl_w, cl_b, out, 393216L, 524288L);

  // ---- cross attention (q = q_l, k/v = k_h) ----
  sf_lin<false><<<GL, blk, 0, stream>>>(S3, A + 98304,  ac_b_in,       nullptr, S0); // qc
  sf_lin<false><<<GL, blk, 0, stream>>>(S2, A + 114688, ac_b_in + 128, nullptr, S1); // kc
  sf_lin<false><<<GL, blk, 0, stream>>>(S2, A + 131072, ac_b_in + 256, nullptr, S4); // vc
  sf_attn<<<2048, blk, 0, stream>>>(S0, S1, S4, S2);                          // S2 = cross attn
  sf_lin<false><<<GL, blk, 0, stream>>>(S2, A + 147456, ac_b_o, nullptr, S1); // S1 = a_cross

  // ---- self attention (q/k/v = q_l) ----
  sf_lin<false><<<GL, blk, 0, stream>>>(S3, A + 163840, as_b_in,       nullptr, S0); // qs
  sf_lin<false><<<GL, blk, 0, stream>>>(S3, A + 180224, as_b_in + 128, nullptr, S2); // ks
  sf_lin<false><<<GL, blk, 0, stream>>>(S3, A + 196608, as_b_in + 256, nullptr, S4); // vs
  sf_attn<<<2048, blk, 0, stream>>>(S0, S2, S4, S3);                          // S3 = self attn
  sf_lin<true><<<GL, blk, 0, stream>>>(S3, A + 212992, as_b_o, S1, S2);       // S2 = fused

  sf_heads<<<512, blk, 0, stream>>>(S2, rf_w, rf_b, cf_w, cf_b, out, 0L, 131072L);
}

// Round 8
// 1015.970 us; speedup vs baseline: 3.0063x; 1.2387x over previous
//
#include <hip/hip_runtime.h>
#include <hip/hip_bf16.h>

// StockFormer forward, MI355X — bf16 MFMA pipeline v2 (MFMA conv, PE table, fused linears).
// B=4, S=256, N=128, F=64, D=E=128, NH=4, HD=32, BN=512, M=131072. Output f32.
typedef __attribute__((ext_vector_type(8))) short short8v;   // 8 bf16 (4 VGPR)
typedef __attribute__((ext_vector_type(4))) float f32x4;
typedef __hip_bfloat16 bh;

constexpr long SF_ELEMS = 131072L * 128;   // elements per ws slot (bf16 -> 32 MiB)
#define MFMA16(a, b, c) __builtin_amdgcn_mfma_f32_16x16x32_bf16((a), (b), (c), 0, 0, 0)

// Arena layout (bf16 elements):
// 0 ta_w_in(49152) | 49152 ta_w_o | 65536 pl | 81920 ph | 98304 ac_w_in(49152) |
// 147456 ac_w_o | 163840 as_w_in(49152) | 212992 as_w_o | 229376 wrep(49152) | end 278528
// then f32 PE table (32768 floats) at byte offset 557056.

// ---------------------------------------------------------------------------
__global__ __launch_bounds__(256) void sf_wcvt(const float* __restrict__ s0, const float* __restrict__ s1,
                                               const float* __restrict__ s2, const float* __restrict__ s3,
                                               const float* __restrict__ s4, const float* __restrict__ s5,
                                               const float* __restrict__ s6, const float* __restrict__ s7,
                                               const float* __restrict__ cw,
                                               bh* __restrict__ dst) {
  int i = blockIdx.x * 256 + threadIdx.x;
  float v;
  if      (i <  49152) v = s0[i];
  else if (i <  65536) v = s1[i - 49152];
  else if (i <  81920) v = s2[i - 65536];
  else if (i <  98304) v = s3[i - 81920];
  else if (i < 147456) v = s4[i - 98304];
  else if (i < 163840) v = s5[i - 147456];
  else if (i < 212992) v = s6[i - 163840];
  else if (i < 229376) v = s7[i - 212992];
  else if (i < 278528) {                       // conv_w repack: wrep[tap][dch][ic]
    int j = i - 229376;
    int tap = j >> 14, rem = j & 16383;        // rem = dch*128+ic
    v = cw[rem * 3 + tap];
  } else return;
  dst[i] = __float2bfloat16(v);
}

// ---------------------------------------------------------------------------
// PE table: pe[s][e] for s in [0,256), e in [0,128)
// ---------------------------------------------------------------------------
__global__ __launch_bounds__(256) void sf_pe(float* __restrict__ pe) {
  int i = blockIdx.x * 256 + threadIdx.x;   // [0, 32768)
  int e = i & 127, s = i >> 7;
  int ii = e >> 1;
  float dv = expf(-0.0719557945041855f * (float)(2 * ii));
  float ang = (float)s * dv;
  pe[i] = (e & 1) ? cosf(ang) : sinf(ang);
}

// ---------------------------------------------------------------------------
// z = xl_cat transposed to (bn,s,e) + PE (table), bf16 store
// ---------------------------------------------------------------------------
__global__ __launch_bounds__(256) void sf_build_z(const float* __restrict__ x,
                                                  const float* __restrict__ pe,
                                                  bh* __restrict__ z) {
  long i = (long)blockIdx.x * 256 + threadIdx.x;
  if (i >= SF_ELEMS) return;
  int e = (int)(i & 127);
  int s = (int)((i >> 7) & 255);
  int r = (int)(i >> 15);
  int b = r >> 7, stk = r & 127;
  float val;
  if (e < 64) {
    val = x[(((long)b * 256 + s) * 128 + stk) * 64 + e];
  } else {
    int f = e - 64;
    int t2 = s >> 1;
    float a0 = x[(((long)b * 256 + 2 * t2) * 128 + stk) * 64 + f];
    float a1 = x[(((long)b * 256 + 2 * t2 + 1) * 128 + stk) * 64 + f];
    val = 0.5f * (a0 + a1);
  }
  z[i] = __float2bfloat16(val + pe[s * 128 + e]);
}

// ---------------------------------------------------------------------------
// xh = xh_cat transposed to (bn,s,ic), bf16
// ---------------------------------------------------------------------------
__global__ __launch_bounds__(256) void sf_build_xh(const float* __restrict__ x,
                                                   bh* __restrict__ xh) {
  long i = (long)blockIdx.x * 256 + threadIdx.x;
  if (i >= SF_ELEMS) return;
  int ic = (int)(i & 127);
  int s = (int)((i >> 7) & 255);
  int r = (int)(i >> 15);
  int b = r >> 7, stk = r & 127;
  float val;
  if (ic < 64) {
    val = x[(((long)b * 256 + s) * 128 + stk) * 64 + ic];
  } else {
    int f = ic - 64;
    int t2 = s >> 1;
    float a0 = x[(((long)b * 256 + 2 * t2) * 128 + stk) * 64 + f];
    float a1 = x[(((long)b * 256 + 2 * t2 + 1) * 128 + stk) * 64 + f];
    float d = 0.5f * (a0 - a1);
    val = (s & 1) ? -d : d;
  }
  xh[i] = __float2bfloat16(val);
}

// ---------------------------------------------------------------------------
// MFMA multi-linear: for q in [0,NW): Yq[M,128] = X[M,128] @ Wq^T + bq
// A-frags held in registers across weight sets (X read once).
// ACC (NW=1 only): Y0 = result + Prev.
// ---------------------------------------------------------------------------
template <int NW, bool ACC>
__global__ __launch_bounds__(256) void sf_linM(const bh* __restrict__ X,
                                               const bh* __restrict__ W0, const bh* __restrict__ W1,
                                               const bh* __restrict__ W2,
                                               const float* __restrict__ b0, const float* __restrict__ b1,
                                               const float* __restrict__ b2,
                                               const bh* __restrict__ Prev,
                                               bh* __restrict__ Y0, bh* __restrict__ Y1,
                                               bh* __restrict__ Y2) {
  const int t = threadIdx.x, lane = t & 63, w = t >> 6;
  const int lr = lane & 15, lg = lane >> 4;
  const long R0 = (long)blockIdx.x * 128 + w * 32;
  const f32x4 z4 = {0.f, 0.f, 0.f, 0.f};
  const bh* Ws[3] = {W0, W1, W2};
  const float* bs[3] = {b0, b1, b2};
  bh* Ys[3] = {Y0, Y1, Y2};
  short8v a[2][4];
#pragma unroll
  for (int ks = 0; ks < 4; ++ks) {
    a[0][ks] = *reinterpret_cast<const short8v*>(X + (R0 + lr) * 128 + ks * 32 + lg * 8);
    a[1][ks] = *reinterpret_cast<const short8v*>(X + (R0 + 16 + lr) * 128 + ks * 32 + lg * 8);
  }
#pragma unroll
  for (int q = 0; q < NW; ++q) {
    f32x4 acc[2][8];
#pragma unroll
    for (int m = 0; m < 2; ++m)
#pragma unroll
      for (int n = 0; n < 8; ++n) acc[m][n] = z4;
#pragma unroll
    for (int ks = 0; ks < 4; ++ks) {
#pragma unroll
      for (int n = 0; n < 8; ++n) {
        short8v b = *reinterpret_cast<const short8v*>(Ws[q] + (long)(n * 16 + lr) * 128 + ks * 32 + lg * 8);
        acc[0][n] = MFMA16(a[0][ks], b, acc[0][n]);
        acc[1][n] = MFMA16(a[1][ks], b, acc[1][n]);
      }
    }
#pragma unroll
    for (int n = 0; n < 8; ++n) {
      float bv = bs[q][n * 16 + lr];
#pragma unroll
      for (int m = 0; m < 2; ++m)
#pragma unroll
        for (int r = 0; r < 4; ++r) {
          long idx = (R0 + m * 16 + 4 * lg + r) * 128 + n * 16 + lr;
          float v = acc[m][n][r] + bv;
          if (ACC) v += __bfloat162float(Prev[idx]);
          Ys[q][idx] = __float2bfloat16(v);
        }
    }
  }
}

// ---------------------------------------------------------------------------
// MFMA dilated conv (k=3 pad2 dil2): out[sc,dch] = relu(b + sum_tap xh[sc+2tap-2]·Wtap^T)
// block = (bnc, half); 4 waves x 32 sc-rows; zero-padded boundary A-frags; no LDS.
// Output into y_h raw-.view() flat layout, bf16.
// ---------------------------------------------------------------------------
__global__ __launch_bounds__(256) void sf_convm(const bh* __restrict__ Xh,
                                                const bh* __restrict__ Wr,
                                                const float* __restrict__ bias,
                                                bh* __restrict__ Yh) {
  const int t = threadIdx.x, lane = t & 63, w = t >> 6;
  const int lr = lane & 15, lg = lane >> 4;
  const int bnc = blockIdx.x >> 1;
  const int half = blockIdx.x & 1;
  const int b = bnc >> 7, stk = bnc & 127;
  const int R0 = half * 128 + w * 32;
  const f32x4 z4 = {0.f, 0.f, 0.f, 0.f};
  const short8v zf = {0, 0, 0, 0, 0, 0, 0, 0};
  f32x4 acc[2][8];
#pragma unroll
  for (int m = 0; m < 2; ++m)
#pragma unroll
    for (int n = 0; n < 8; ++n) acc[m][n] = z4;
#pragma unroll
  for (int tap = 0; tap < 3; ++tap) {
    const int shift = 2 * tap - 2;
#pragma unroll
    for (int ks = 0; ks < 4; ++ks) {
      int s0 = R0 + lr + shift;
      int s1 = s0 + 16;
      short8v a0 = zf, a1 = zf;
      if ((unsigned)s0 < 256u)
        a0 = *reinterpret_cast<const short8v*>(Xh + ((long)bnc * 256 + s0) * 128 + ks * 32 + lg * 8);
      if ((unsigned)s1 < 256u)
        a1 = *reinterpret_cast<const short8v*>(Xh + ((long)bnc * 256 + s1) * 128 + ks * 32 + lg * 8);
#pragma unroll
      for (int n = 0; n < 8; ++n) {
        short8v bb = *reinterpret_cast<const short8v*>(Wr + (long)tap * 16384 + (long)(n * 16 + lr) * 128 + ks * 32 + lg * 8);
        acc[0][n] = MFMA16(a0, bb, acc[0][n]);
        acc[1][n] = MFMA16(a1, bb, acc[1][n]);
      }
    }
  }
#pragma unroll
  for (int n = 0; n < 8; ++n) {
    float bv = bias[n * 16 + lr];
#pragma unroll
    for (int m = 0; m < 2; ++m)
#pragma unroll
      for (int r = 0; r < 4; ++r) {
        int sc = R0 + m * 16 + 4 * lg + r;
        int rp = b * 128 + (sc >> 1);
        int sp = ((sc & 1) << 7) + stk;
        float v = fmaxf(acc[m][n][r] + bv, 0.f);
        Yh[((long)rp * 256 + sp) * 128 + n * 16 + lr] = __float2bfloat16(v);
      }
  }
}

// ---------------------------------------------------------------------------
// MFMA flash attention (unchanged from r7, verified).
// ---------------------------------------------------------------------------
__global__ __launch_bounds__(256) void sf_attn(const bh* __restrict__ Q, const bh* __restrict__ K,
                                               const bh* __restrict__ V, bh* __restrict__ O) {
  __shared__ bh Ks[64][72];
  __shared__ bh Vt[32][72];
  __shared__ bh Pl[4][16][72];
  const int t = threadIdx.x, lane = t & 63, w = t >> 6;
  const int lr = lane & 15, lg = lane >> 4;
  const int bn = blockIdx.x >> 2, h = blockIdx.x & 3;
  const long R0 = (long)bn * 256;
  const int ch = h * 32;
  short8v aq[4];
#pragma unroll
  for (int mt = 0; mt < 4; ++mt)
    aq[mt] = *reinterpret_cast<const short8v*>(Q + (R0 + w * 64 + mt * 16 + lr) * 128 + ch + lg * 8);
  const f32x4 z4 = {0.f, 0.f, 0.f, 0.f};
  f32x4 Oacc[4][2];
  float ms[4][4], ls[4][4];
#pragma unroll
  for (int mt = 0; mt < 4; ++mt) {
    Oacc[mt][0] = z4; Oacc[mt][1] = z4;
#pragma unroll
    for (int r = 0; r < 4; ++r) { ms[mt][r] = -1e30f; ls[mt][r] = 0.f; }
  }
  const float scale = 0.17677669529663687f;  // 1/sqrt(32)
  for (int kt = 0; kt < 4; ++kt) {
    __syncthreads();
    {
      const int kr = t >> 2, cg = (t & 3) * 8;
      short8v kv = *reinterpret_cast<const short8v*>(K + (R0 + kt * 64 + kr) * 128 + ch + cg);
      *reinterpret_cast<short8v*>(&Ks[kr][cg]) = kv;
      short8v vv = *reinterpret_cast<const short8v*>(V + (R0 + kt * 64 + kr) * 128 + ch + cg);
      const bh* vp = reinterpret_cast<const bh*>(&vv);
#pragma unroll
      for (int j = 0; j < 8; ++j) Vt[cg + j][kr] = vp[j];
    }
    __syncthreads();
    short8v bv[2][2];
#pragma unroll
    for (int dt = 0; dt < 2; ++dt)
#pragma unroll
      for (int ks = 0; ks < 2; ++ks)
        bv[dt][ks] = *reinterpret_cast<const short8v*>(&Vt[dt * 16 + lr][ks * 32 + lg * 8]);
#pragma unroll
    for (int mt = 0; mt < 4; ++mt) {
      f32x4 S[4];
#pragma unroll
      for (int nt = 0; nt < 4; ++nt) {
        short8v bk = *reinterpret_cast<const short8v*>(&Ks[nt * 16 + lr][lg * 8]);
        S[nt] = MFMA16(aq[mt], bk, z4);
      }
#pragma unroll
      for (int r = 0; r < 4; ++r) {
        float s0 = S[0][r] * scale, s1 = S[1][r] * scale;
        float s2 = S[2][r] * scale, s3 = S[3][r] * scale;
        float tm = fmaxf(fmaxf(s0, s1), fmaxf(s2, s3));
        tm = fmaxf(tm, __shfl_xor(tm, 1, 64));
        tm = fmaxf(tm, __shfl_xor(tm, 2, 64));
        tm = fmaxf(tm, __shfl_xor(tm, 4, 64));
        tm = fmaxf(tm, __shfl_xor(tm, 8, 64));
        float mold = ms[mt][r];
        float mnew = fmaxf(mold, tm);
        float corr = __expf(mold - mnew);
        float p0 = __expf(s0 - mnew), p1 = __expf(s1 - mnew);
        float p2 = __expf(s2 - mnew), p3 = __expf(s3 - mnew);
        bh* pr = &Pl[w][4 * lg + r][lr];
        pr[0]  = __float2bfloat16(p0);
        pr[16] = __float2bfloat16(p1);
        pr[32] = __float2bfloat16(p2);
        pr[48] = __float2bfloat16(p3);
        float rs = p0 + p1 + p2 + p3;
        rs += __shfl_xor(rs, 1, 64); rs += __shfl_xor(rs, 2, 64);
        rs += __shfl_xor(rs, 4, 64); rs += __shfl_xor(rs, 8, 64);
        ls[mt][r] = ls[mt][r] * corr + rs;
        ms[mt][r] = mnew;
        Oacc[mt][0][r] *= corr;
        Oacc[mt][1][r] *= corr;
      }
#pragma unroll
      for (int ks = 0; ks < 2; ++ks) {
        short8v ap = *reinterpret_cast<const short8v*>(&Pl[w][lr][ks * 32 + lg * 8]);
        Oacc[mt][0] = MFMA16(ap, bv[0][ks], Oacc[mt][0]);
        Oacc[mt][1] = MFMA16(ap, bv[1][ks], Oacc[mt][1]);
      }
    }
  }
#pragma unroll
  for (int mt = 0; mt < 4; ++mt)
#pragma unroll
    for (int r = 0; r < 4; ++r) {
      float inv = 1.f / ls[mt][r];
      long row = R0 + w * 64 + mt * 16 + 4 * lg + r;
      O[row * 128 + ch + lr]      = __float2bfloat16(Oacc[mt][0][r] * inv);
      O[row * 128 + ch + 16 + lr] = __float2bfloat16(Oacc[mt][1][r] * inv);
    }
}

// ---------------------------------------------------------------------------
// heads: reg = X@rw^T+rb ; cla = softmax2(X@cw^T+cb); bf16 in, f32 out (idx=row)
// ---------------------------------------------------------------------------
__global__ __launch_bounds__(256) void sf_heads(const bh* __restrict__ X,
                                                const float* __restrict__ rw,
                                                const float* __restrict__ rb,
                                                const float* __restrict__ cw,
                                                const float* __restrict__ cb,
                                                float* __restrict__ out,
                                                long off_reg, long off_cla) {
  __shared__ float w0[128], w1[128], w2[128];
  const int t = threadIdx.x;
  if (t < 128) { w0[t] = rw[t]; w1[t] = cw[t]; w2[t] = cw[128 + t]; }
  __syncthreads();
  long row = (long)blockIdx.x * 256 + t;
  const bh* xr = X + row * 128;
  float d0 = 0.f, d1 = 0.f, d2 = 0.f;
#pragma unroll 4
  for (int j = 0; j < 128; j += 8) {
    short8v v8 = *reinterpret_cast<const short8v*>(xr + j);
    const bh* vv = reinterpret_cast<const bh*>(&v8);
#pragma unroll
    for (int k = 0; k < 8; ++k) {
      float f = __bfloat162float(vv[k]);
      d0 = fmaf(f, w0[j + k], d0);
      d1 = fmaf(f, w1[j + k], d1);
      d2 = fmaf(f, w2[j + k], d2);
    }
  }
  d0 += rb[0]; d1 += cb[0]; d2 += cb[1];
  float mx = fmaxf(d1, d2);
  float e1 = expf(d1 - mx), e2 = expf(d2 - mx);
  float inv = 1.f / (e1 + e2);
  out[off_reg + row] = d0;
  out[off_cla + row * 2] = e1 * inv;
  out[off_cla + row * 2 + 1] = e2 * inv;
}

// ---------------------------------------------------------------------------
extern "C" void kernel_launch(void* const* d_in, const int* in_sizes, int n_in,
                              void* d_out, int out_size, void* d_ws, size_t ws_size,
                              hipStream_t stream) {
  (void)in_sizes; (void)n_in; (void)out_size; (void)ws_size;
  const float* x       = (const float*)d_in[0];
  const float* ta_w_in = (const float*)d_in[2];
  const float* ta_b_in = (const float*)d_in[3];
  const float* ta_w_o  = (const float*)d_in[4];
  const float* ta_b_o  = (const float*)d_in[5];
  const float* conv_w  = (const float*)d_in[6];
  const float* conv_b  = (const float*)d_in[7];
  const float* pl_w    = (const float*)d_in[8];
  const float* pl_b    = (const float*)d_in[9];
  const float* ph_w    = (const float*)d_in[10];
  const float* ph_b    = (const float*)d_in[11];
  const float* as_w_in = (const float*)d_in[12];
  const float* as_b_in = (const float*)d_in[13];
  const float* as_w_o  = (const float*)d_in[14];
  const float* as_b_o  = (const float*)d_in[15];
  const float* ac_w_in = (const float*)d_in[16];
  const float* ac_b_in = (const float*)d_in[17];
  const float* ac_w_o  = (const float*)d_in[18];
  const float* ac_b_o  = (const float*)d_in[19];
  const float* rl_w    = (const float*)d_in[20];
  const float* rl_b    = (const float*)d_in[21];
  const float* cl_w    = (const float*)d_in[22];
  const float* cl_b    = (const float*)d_in[23];
  const float* rf_w    = (const float*)d_in[24];
  const float* rf_b    = (const float*)d_in[25];
  const float* cf_w    = (const float*)d_in[26];
  const float* cf_b    = (const float*)d_in[27];
  float* out = (float*)d_out;

  bh* S0 = (bh*)d_ws;                 // 5 slots x 32 MiB + ~0.7 MiB tail
  bh* S1 = S0 + SF_ELEMS;
  bh* S2 = S1 + SF_ELEMS;
  bh* S3 = S2 + SF_ELEMS;
  bh* S4 = S3 + SF_ELEMS;
  bh* A  = S4 + SF_ELEMS;             // bf16 arena (278528)
  float* PE = (float*)(A + 278528);   // 32768 f32

  dim3 blk(256);
  const int GZ = (int)(SF_ELEMS / 256);
  const int GL = 1024;                // 131072 / 128
  const bh* np = nullptr;
  float* nf = nullptr;

  sf_wcvt<<<1088, blk, 0, stream>>>(ta_w_in, ta_w_o, pl_w, ph_w, ac_w_in, ac_w_o,
                                    as_w_in, as_w_o, conv_w, A);
  sf_pe<<<128, blk, 0, stream>>>(PE);

  // ---- encoder ----
  sf_build_z<<<GZ, blk, 0, stream>>>(x, PE, S0);                              // S0 = z
  sf_linM<3, false><<<GL, blk, 0, stream>>>(S0, A, A + 16384, A + 32768,
                                            ta_b_in, ta_b_in + 128, ta_b_in + 256,
                                            np, S1, S2, S3);                  // Q,K,V
  sf_attn<<<2048, blk, 0, stream>>>(S1, S2, S3, S4);                          // S4 = enc attn
  sf_linM<1, false><<<GL, blk, 0, stream>>>(S4, A + 49152, np, np,
                                            ta_b_o, nf, nf, np, S0, nullptr, nullptr); // y_l
  sf_build_xh<<<GZ, blk, 0, stream>>>(x, S1);                                 // S1 = xh
  sf_convm<<<1024, blk, 0, stream>>>(S1, A + 229376, conv_b, S2);             // S2 = y_h

  // ---- decoder projections + aux heads ----
  sf_linM<1, false><<<GL, blk, 0, stream>>>(S2, A + 81920, np, np, ph_b, nf, nf,
                                            np, S3, nullptr, nullptr);        // S3 = k_h
  sf_linM<1, false><<<GL, blk, 0, stream>>>(S0, A + 65536, np, np, pl_b, nf, nf,
                                            np, S1, nullptr, nullptr);        // S1 = q_l
  sf_linM<1, false><<<GL, blk, 0, stream>>>(S1, A + 65536, np, np, pl_b, nf, nf,
                                            np, S4, nullptr, nullptr);        // S4 = y_l2
  sf_heads<<<512, blk, 0, stream>>>(S4, rl_w, rl_b, cl_w, cl_b, out, 393216L, 524288L);

  // ---- cross attention (q = q_l, k/v = k_h) ----
  sf_linM<1, false><<<GL, blk, 0, stream>>>(S1, A + 98304, np, np, ac_b_in, nf, nf,
                                            np, S0, nullptr, nullptr);        // qc
  sf_linM<2, false><<<GL, blk, 0, stream>>>(S3, A + 114688, A + 131072, np,
                                            ac_b_in + 128, ac_b_in + 256, nf,
                                            np, S2, S4, nullptr);             // kc, vc
  sf_attn<<<2048, blk, 0, stream>>>(S0, S2, S4, S3);                          // S3 = cross attn
  sf_linM<1, false><<<GL, blk, 0, stream>>>(S3, A + 147456, np, np, ac_b_o, nf, nf,
                                            np, S2, nullptr, nullptr);        // S2 = a_cross

  // ---- self attention (q/k/v = q_l) ----
  sf_linM<3, false><<<GL, blk, 0, stream>>>(S1, A + 163840, A + 180224, A + 196608,
                                            as_b_in, as_b_in + 128, as_b_in + 256,
                                            np, S0, S4, S3);                  // qs,ks,vs
  sf_attn<<<2048, blk, 0, stream>>>(S0, S4, S3, S1);                          // S1 = self attn
  sf_linM<1, true><<<GL, blk, 0, stream>>>(S1, A + 212992, np, np, as_b_o, nf, nf,
                                           S2, S4, nullptr, nullptr);         // S4 = fused

  sf_heads<<<512, blk, 0, stream>>>(S4, rf_w, rf_b, cf_w, cf_b, out, 0L, 131072L);
}

// Round 9
// 701.322 us; speedup vs baseline: 4.3551x; 1.4486x over previous
//
#include <hip/hip_runtime.h>
#include <hip/hip_bf16.h>

// StockFormer forward, MI355X — bf16 MFMA pipeline v3 (no-max exp attention, swapped QK^T).
// B=4, S=256, N=128, F=64, D=E=128, NH=4, HD=32, BN=512, M=131072. Output f32.
typedef __attribute__((ext_vector_type(8))) short short8v;   // 8 bf16 (4 VGPR)
typedef __attribute__((ext_vector_type(4))) short short4v;   // 4 bf16 (2 VGPR)
typedef __attribute__((ext_vector_type(4))) float f32x4;
typedef __hip_bfloat16 bh;

constexpr long SF_ELEMS = 131072L * 128;   // elements per ws slot (bf16 -> 32 MiB)
#define MFMA16(a, b, c) __builtin_amdgcn_mfma_f32_16x16x32_bf16((a), (b), (c), 0, 0, 0)

__device__ __forceinline__ short bh_bits(float x) {
  bh h = __float2bfloat16(x);
  return *reinterpret_cast<short*>(&h);
}

// Arena layout (bf16 elements):
// 0 ta_w_in(49152) | 49152 ta_w_o | 65536 pl | 81920 ph | 98304 ac_w_in(49152) |
// 147456 ac_w_o | 163840 as_w_in(49152) | 212992 as_w_o | 229376 wrep(49152) | end 278528
// then f32 PE table (32768 floats).

// ---------------------------------------------------------------------------
__global__ __launch_bounds__(256) void sf_wcvt(const float* __restrict__ s0, const float* __restrict__ s1,
                                               const float* __restrict__ s2, const float* __restrict__ s3,
                                               const float* __restrict__ s4, const float* __restrict__ s5,
                                               const float* __restrict__ s6, const float* __restrict__ s7,
                                               const float* __restrict__ cw,
                                               bh* __restrict__ dst) {
  int i = blockIdx.x * 256 + threadIdx.x;
  float v;
  if      (i <  49152) v = s0[i];
  else if (i <  65536) v = s1[i - 49152];
  else if (i <  81920) v = s2[i - 65536];
  else if (i <  98304) v = s3[i - 81920];
  else if (i < 147456) v = s4[i - 98304];
  else if (i < 163840) v = s5[i - 147456];
  else if (i < 212992) v = s6[i - 163840];
  else if (i < 229376) v = s7[i - 212992];
  else if (i < 278528) {                       // conv_w repack: wrep[tap][dch][ic]
    int j = i - 229376;
    int tap = j >> 14, rem = j & 16383;
    v = cw[rem * 3 + tap];
  } else return;
  dst[i] = __float2bfloat16(v);
}

// ---------------------------------------------------------------------------
__global__ __launch_bounds__(256) void sf_pe(float* __restrict__ pe) {
  int i = blockIdx.x * 256 + threadIdx.x;   // [0, 32768)
  int e = i & 127, s = i >> 7;
  int ii = e >> 1;
  float dv = expf(-0.0719557945041855f * (float)(2 * ii));
  float ang = (float)s * dv;
  pe[i] = (e & 1) ? cosf(ang) : sinf(ang);
}

// ---------------------------------------------------------------------------
__global__ __launch_bounds__(256) void sf_build_z(const float* __restrict__ x,
                                                  const float* __restrict__ pe,
                                                  bh* __restrict__ z) {
  long i = (long)blockIdx.x * 256 + threadIdx.x;
  if (i >= SF_ELEMS) return;
  int e = (int)(i & 127);
  int s = (int)((i >> 7) & 255);
  int r = (int)(i >> 15);
  int b = r >> 7, stk = r & 127;
  float val;
  if (e < 64) {
    val = x[(((long)b * 256 + s) * 128 + stk) * 64 + e];
  } else {
    int f = e - 64;
    int t2 = s >> 1;
    float a0 = x[(((long)b * 256 + 2 * t2) * 128 + stk) * 64 + f];
    float a1 = x[(((long)b * 256 + 2 * t2 + 1) * 128 + stk) * 64 + f];
    val = 0.5f * (a0 + a1);
  }
  z[i] = __float2bfloat16(val + pe[s * 128 + e]);
}

// ---------------------------------------------------------------------------
__global__ __launch_bounds__(256) void sf_build_xh(const float* __restrict__ x,
                                                   bh* __restrict__ xh) {
  long i = (long)blockIdx.x * 256 + threadIdx.x;
  if (i >= SF_ELEMS) return;
  int ic = (int)(i & 127);
  int s = (int)((i >> 7) & 255);
  int r = (int)(i >> 15);
  int b = r >> 7, stk = r & 127;
  float val;
  if (ic < 64) {
    val = x[(((long)b * 256 + s) * 128 + stk) * 64 + ic];
  } else {
    int f = ic - 64;
    int t2 = s >> 1;
    float a0 = x[(((long)b * 256 + 2 * t2) * 128 + stk) * 64 + f];
    float a1 = x[(((long)b * 256 + 2 * t2 + 1) * 128 + stk) * 64 + f];
    float d = 0.5f * (a0 - a1);
    val = (s & 1) ? -d : d;
  }
  xh[i] = __float2bfloat16(val);
}

// ---------------------------------------------------------------------------
// MFMA multi-linear: for q in [0,NW): Yq[M,128] = X[M,128] @ Wq^T + bq
// ---------------------------------------------------------------------------
template <int NW, bool ACC>
__global__ __launch_bounds__(256) void sf_linM(const bh* __restrict__ X,
                                               const bh* __restrict__ W0, const bh* __restrict__ W1,
                                               const bh* __restrict__ W2,
                                               const float* __restrict__ b0, const float* __restrict__ b1,
                                               const float* __restrict__ b2,
                                               const bh* __restrict__ Prev,
                                               bh* __restrict__ Y0, bh* __restrict__ Y1,
                                               bh* __restrict__ Y2) {
  const int t = threadIdx.x, lane = t & 63, w = t >> 6;
  const int lr = lane & 15, lg = lane >> 4;
  const long R0 = (long)blockIdx.x * 128 + w * 32;
  const f32x4 z4 = {0.f, 0.f, 0.f, 0.f};
  const bh* Ws[3] = {W0, W1, W2};
  const float* bs[3] = {b0, b1, b2};
  bh* Ys[3] = {Y0, Y1, Y2};
  short8v a[2][4];
#pragma unroll
  for (int ks = 0; ks < 4; ++ks) {
    a[0][ks] = *reinterpret_cast<const short8v*>(X + (R0 + lr) * 128 + ks * 32 + lg * 8);
    a[1][ks] = *reinterpret_cast<const short8v*>(X + (R0 + 16 + lr) * 128 + ks * 32 + lg * 8);
  }
#pragma unroll
  for (int q = 0; q < NW; ++q) {
    f32x4 acc[2][8];
#pragma unroll
    for (int m = 0; m < 2; ++m)
#pragma unroll
      for (int n = 0; n < 8; ++n) acc[m][n] = z4;
#pragma unroll
    for (int ks = 0; ks < 4; ++ks) {
#pragma unroll
      for (int n = 0; n < 8; ++n) {
        short8v b = *reinterpret_cast<const short8v*>(Ws[q] + (long)(n * 16 + lr) * 128 + ks * 32 + lg * 8);
        acc[0][n] = MFMA16(a[0][ks], b, acc[0][n]);
        acc[1][n] = MFMA16(a[1][ks], b, acc[1][n]);
      }
    }
#pragma unroll
    for (int n = 0; n < 8; ++n) {
      float bv = bs[q][n * 16 + lr];
#pragma unroll
      for (int m = 0; m < 2; ++m)
#pragma unroll
        for (int r = 0; r < 4; ++r) {
          long idx = (R0 + m * 16 + 4 * lg + r) * 128 + n * 16 + lr;
          float v = acc[m][n][r] + bv;
          if (ACC) v += __bfloat162float(Prev[idx]);
          Ys[q][idx] = __float2bfloat16(v);
        }
    }
  }
}

// ---------------------------------------------------------------------------
// MFMA dilated conv (k=3 pad2 dil2), no LDS, y_h flat-layout output.
// ---------------------------------------------------------------------------
__global__ __launch_bounds__(256) void sf_convm(const bh* __restrict__ Xh,
                                                const bh* __restrict__ Wr,
                                                const float* __restrict__ bias,
                                                bh* __restrict__ Yh) {
  const int t = threadIdx.x, lane = t & 63, w = t >> 6;
  const int lr = lane & 15, lg = lane >> 4;
  const int bnc = blockIdx.x >> 1;
  const int half = blockIdx.x & 1;
  const int b = bnc >> 7, stk = bnc & 127;
  const int R0 = half * 128 + w * 32;
  const f32x4 z4 = {0.f, 0.f, 0.f, 0.f};
  const short8v zf = {0, 0, 0, 0, 0, 0, 0, 0};
  f32x4 acc[2][8];
#pragma unroll
  for (int m = 0; m < 2; ++m)
#pragma unroll
    for (int n = 0; n < 8; ++n) acc[m][n] = z4;
#pragma unroll
  for (int tap = 0; tap < 3; ++tap) {
    const int shift = 2 * tap - 2;
#pragma unroll
    for (int ks = 0; ks < 4; ++ks) {
      int s0 = R0 + lr + shift;
      int s1 = s0 + 16;
      short8v a0 = zf, a1 = zf;
      if ((unsigned)s0 < 256u)
        a0 = *reinterpret_cast<const short8v*>(Xh + ((long)bnc * 256 + s0) * 128 + ks * 32 + lg * 8);
      if ((unsigned)s1 < 256u)
        a1 = *reinterpret_cast<const short8v*>(Xh + ((long)bnc * 256 + s1) * 128 + ks * 32 + lg * 8);
#pragma unroll
      for (int n = 0; n < 8; ++n) {
        short8v bb = *reinterpret_cast<const short8v*>(Wr + (long)tap * 16384 + (long)(n * 16 + lr) * 128 + ks * 32 + lg * 8);
        acc[0][n] = MFMA16(a0, bb, acc[0][n]);
        acc[1][n] = MFMA16(a1, bb, acc[1][n]);
      }
    }
  }
#pragma unroll
  for (int n = 0; n < 8; ++n) {
    float bv = bias[n * 16 + lr];
#pragma unroll
    for (int m = 0; m < 2; ++m)
#pragma unroll
      for (int r = 0; r < 4; ++r) {
        int sc = R0 + m * 16 + 4 * lg + r;
        int rp = b * 128 + (sc >> 1);
        int sp = ((sc & 1) << 7) + stk;
        float v = fmaxf(acc[m][n][r] + bv, 0.f);
        Yh[((long)rp * 256 + sp) * 128 + n * 16 + lr] = __float2bfloat16(v);
      }
  }
}

// ---------------------------------------------------------------------------
// MFMA attention v3: block=(bn,h), 4 waves x 64 q-rows, kv-tiles of 64.
// No max subtraction (scores are O(1) by weight scale; softmax shift-invariant).
// S^T = MFMA16(K-frag, Q-frag): lane owns q-row = lane&15, k = kt*64+nt*16+4*lg+r
//  -> row-sum is lane-local (+2 shfl_xor at end); P written as 4x ds_write_b64.
// PV: O += MFMA16(P-frag, Vt-frag) (unchanged convention).
// ---------------------------------------------------------------------------
__global__ __launch_bounds__(256) void sf_attn(const bh* __restrict__ Q, const bh* __restrict__ K,
                                               const bh* __restrict__ V, bh* __restrict__ O) {
  __shared__ bh Ks[64][80];
  __shared__ bh Vt[32][80];
  __shared__ bh Pl[4][16][80];
  const int t = threadIdx.x, lane = t & 63, w = t >> 6;
  const int lr = lane & 15, lg = lane >> 4;
  const int bn = blockIdx.x >> 2, h = blockIdx.x & 3;
  const long R0 = (long)bn * 256;
  const int ch = h * 32;
  const float sc = 0.17677669529663687f;  // 1/sqrt(32)
  short8v aq[4];
#pragma unroll
  for (int mt = 0; mt < 4; ++mt)
    aq[mt] = *reinterpret_cast<const short8v*>(Q + (R0 + w * 64 + mt * 16 + lr) * 128 + ch + lg * 8);
  const f32x4 z4 = {0.f, 0.f, 0.f, 0.f};
  f32x4 Oacc[4][2];
  float psum[4] = {0.f, 0.f, 0.f, 0.f};
#pragma unroll
  for (int mt = 0; mt < 4; ++mt) { Oacc[mt][0] = z4; Oacc[mt][1] = z4; }
  for (int kt = 0; kt < 4; ++kt) {
    __syncthreads();
    {
      const int kr = t >> 2, cg = (t & 3) * 8;
      short8v kv = *reinterpret_cast<const short8v*>(K + (R0 + kt * 64 + kr) * 128 + ch + cg);
      *reinterpret_cast<short8v*>(&Ks[kr][cg]) = kv;
      short8v vv = *reinterpret_cast<const short8v*>(V + (R0 + kt * 64 + kr) * 128 + ch + cg);
      const bh* vp = reinterpret_cast<const bh*>(&vv);
#pragma unroll
      for (int j = 0; j < 8; ++j) Vt[cg + j][kr] = vp[j];
    }
    __syncthreads();
    short8v bv[2][2];
#pragma unroll
    for (int dt = 0; dt < 2; ++dt)
#pragma unroll
      for (int ks = 0; ks < 2; ++ks)
        bv[dt][ks] = *reinterpret_cast<const short8v*>(&Vt[dt * 16 + lr][ks * 32 + lg * 8]);
#pragma unroll
    for (int mt = 0; mt < 4; ++mt) {
      f32x4 st[4];
#pragma unroll
      for (int nt = 0; nt < 4; ++nt) {
        short8v bk = *reinterpret_cast<const short8v*>(&Ks[nt * 16 + lr][lg * 8]);
        st[nt] = MFMA16(bk, aq[mt], z4);     // S^T = K·Q^T (swapped operands)
      }
      float ps = 0.f;
#pragma unroll
      for (int nt = 0; nt < 4; ++nt) {
        float p0 = __expf(st[nt][0] * sc);
        float p1 = __expf(st[nt][1] * sc);
        float p2 = __expf(st[nt][2] * sc);
        float p3 = __expf(st[nt][3] * sc);
        ps += (p0 + p1) + (p2 + p3);
        short4v pk;
        pk[0] = bh_bits(p0); pk[1] = bh_bits(p1); pk[2] = bh_bits(p2); pk[3] = bh_bits(p3);
        *reinterpret_cast<short4v*>(&Pl[w][lr][nt * 16 + 4 * lg]) = pk;   // b64 store
      }
      psum[mt] += ps;
#pragma unroll
      for (int ks = 0; ks < 2; ++ks) {
        short8v ap = *reinterpret_cast<const short8v*>(&Pl[w][lr][ks * 32 + lg * 8]);
        Oacc[mt][0] = MFMA16(ap, bv[0][ks], Oacc[mt][0]);
        Oacc[mt][1] = MFMA16(ap, bv[1][ks], Oacc[mt][1]);
      }
    }
  }
#pragma unroll
  for (int mt = 0; mt < 4; ++mt) {
    float ps = psum[mt];
    ps += __shfl_xor(ps, 16, 64);
    ps += __shfl_xor(ps, 32, 64);
    float inv = 1.f / ps;                    // valid on lanes sharing lr; q-row = lr
#pragma unroll
    for (int r = 0; r < 4; ++r) {
      float invr = __shfl(inv, 4 * lg + r, 64);   // fetch inv of q-row 4*lg+r
      long row = R0 + w * 64 + mt * 16 + 4 * lg + r;
      O[row * 128 + ch + lr]      = __float2bfloat16(Oacc[mt][0][r] * invr);
      O[row * 128 + ch + 16 + lr] = __float2bfloat16(Oacc[mt][1][r] * invr);
    }
  }
}

// ---------------------------------------------------------------------------
// heads: reg = X@rw^T+rb ; cla = softmax2(X@cw^T+cb); bf16 in, f32 out (idx=row)
// ---------------------------------------------------------------------------
__global__ __launch_bounds__(256) void sf_heads(const bh* __restrict__ X,
                                                const float* __restrict__ rw,
                                                const float* __restrict__ rb,
                                                const float* __restrict__ cw,
                                                const float* __restrict__ cb,
                                                float* __restrict__ out,
                                                long off_reg, long off_cla) {
  __shared__ float w0[128], w1[128], w2[128];
  const int t = threadIdx.x;
  if (t < 128) { w0[t] = rw[t]; w1[t] = cw[t]; w2[t] = cw[128 + t]; }
  __syncthreads();
  long row = (long)blockIdx.x * 256 + t;
  const bh* xr = X + row * 128;
  float d0 = 0.f, d1 = 0.f, d2 = 0.f;
#pragma unroll 4
  for (int j = 0; j < 128; j += 8) {
    short8v v8 = *reinterpret_cast<const short8v*>(xr + j);
    const bh* vv = reinterpret_cast<const bh*>(&v8);
#pragma unroll
    for (int k = 0; k < 8; ++k) {
      float f = __bfloat162float(vv[k]);
      d0 = fmaf(f, w0[j + k], d0);
      d1 = fmaf(f, w1[j + k], d1);
      d2 = fmaf(f, w2[j + k], d2);
    }
  }
  d0 += rb[0]; d1 += cb[0]; d2 += cb[1];
  float mx = fmaxf(d1, d2);
  float e1 = expf(d1 - mx), e2 = expf(d2 - mx);
  float inv = 1.f / (e1 + e2);
  out[off_reg + row] = d0;
  out[off_cla + row * 2] = e1 * inv;
  out[off_cla + row * 2 + 1] = e2 * inv;
}

// ---------------------------------------------------------------------------
extern "C" void kernel_launch(void* const* d_in, const int* in_sizes, int n_in,
                              void* d_out, int out_size, void* d_ws, size_t ws_size,
                              hipStream_t stream) {
  (void)in_sizes; (void)n_in; (void)out_size; (void)ws_size;
  const float* x       = (const float*)d_in[0];
  const float* ta_w_in = (const float*)d_in[2];
  const float* ta_b_in = (const float*)d_in[3];
  const float* ta_w_o  = (const float*)d_in[4];
  const float* ta_b_o  = (const float*)d_in[5];
  const float* conv_w  = (const float*)d_in[6];
  const float* conv_b  = (const float*)d_in[7];
  const float* pl_w    = (const float*)d_in[8];
  const float* pl_b    = (const float*)d_in[9];
  const float* ph_w    = (const float*)d_in[10];
  const float* ph_b    = (const float*)d_in[11];
  const float* as_w_in = (const float*)d_in[12];
  const float* as_b_in = (const float*)d_in[13];
  const float* as_w_o  = (const float*)d_in[14];
  const float* as_b_o  = (const float*)d_in[15];
  const float* ac_w_in = (const float*)d_in[16];
  const float* ac_b_in = (const float*)d_in[17];
  const float* ac_w_o  = (const float*)d_in[18];
  const float* ac_b_o  = (const float*)d_in[19];
  const float* rl_w    = (const float*)d_in[20];
  const float* rl_b    = (const float*)d_in[21];
  const float* cl_w    = (const float*)d_in[22];
  const float* cl_b    = (const float*)d_in[23];
  const float* rf_w    = (const float*)d_in[24];
  const float* rf_b    = (const float*)d_in[25];
  const float* cf_w    = (const float*)d_in[26];
  const float* cf_b    = (const float*)d_in[27];
  float* out = (float*)d_out;

  bh* S0 = (bh*)d_ws;
  bh* S1 = S0 + SF_ELEMS;
  bh* S2 = S1 + SF_ELEMS;
  bh* S3 = S2 + SF_ELEMS;
  bh* S4 = S3 + SF_ELEMS;
  bh* A  = S4 + SF_ELEMS;             // bf16 arena (278528)
  float* PE = (float*)(A + 278528);   // 32768 f32

  dim3 blk(256);
  const int GZ = (int)(SF_ELEMS / 256);
  const int GL = 1024;                // 131072 / 128
  const bh* np = nullptr;
  float* nf = nullptr;

  sf_wcvt<<<1088, blk, 0, stream>>>(ta_w_in, ta_w_o, pl_w, ph_w, ac_w_in, ac_w_o,
                                    as_w_in, as_w_o, conv_w, A);
  sf_pe<<<128, blk, 0, stream>>>(PE);

  // ---- encoder ----
  sf_build_z<<<GZ, blk, 0, stream>>>(x, PE, S0);                              // S0 = z
  sf_linM<3, false><<<GL, blk, 0, stream>>>(S0, A, A + 16384, A + 32768,
                                            ta_b_in, ta_b_in + 128, ta_b_in + 256,
                                            np, S1, S2, S3);                  // Q,K,V
  sf_attn<<<2048, blk, 0, stream>>>(S1, S2, S3, S4);                          // S4 = enc attn
  sf_linM<1, false><<<GL, blk, 0, stream>>>(S4, A + 49152, np, np,
                                            ta_b_o, nf, nf, np, S0, nullptr, nullptr); // y_l
  sf_build_xh<<<GZ, blk, 0, stream>>>(x, S1);                                 // S1 = xh
  sf_convm<<<1024, blk, 0, stream>>>(S1, A + 229376, conv_b, S2);             // S2 = y_h

  // ---- decoder projections + aux heads ----
  sf_linM<1, false><<<GL, blk, 0, stream>>>(S2, A + 81920, np, np, ph_b, nf, nf,
                                            np, S3, nullptr, nullptr);        // S3 = k_h
  sf_linM<1, false><<<GL, blk, 0, stream>>>(S0, A + 65536, np, np, pl_b, nf, nf,
                                            np, S1, nullptr, nullptr);        // S1 = q_l
  sf_linM<1, false><<<GL, blk, 0, stream>>>(S1, A + 65536, np, np, pl_b, nf, nf,
                                            np, S4, nullptr, nullptr);        // S4 = y_l2
  sf_heads<<<512, blk, 0, stream>>>(S4, rl_w, rl_b, cl_w, cl_b, out, 393216L, 524288L);

  // ---- cross attention (q = q_l, k/v = k_h) ----
  sf_linM<1, false><<<GL, blk, 0, stream>>>(S1, A + 98304, np, np, ac_b_in, nf, nf,
                                            np, S0, nullptr, nullptr);        // qc
  sf_linM<2, false><<<GL, blk, 0, stream>>>(S3, A + 114688, A + 131072, np,
                                            ac_b_in + 128, ac_b_in + 256, nf,
                                            np, S2, S4, nullptr);             // kc, vc
  sf_attn<<<2048, blk, 0, stream>>>(S0, S2, S4, S3);                          // S3 = cross attn
  sf_linM<1, false><<<GL, blk, 0, stream>>>(S3, A + 147456, np, np, ac_b_o, nf, nf,
                                            np, S2, nullptr, nullptr);        // S2 = a_cross

  // ---- self attention (q/k/v = q_l) ----
  sf_linM<3, false><<<GL, blk, 0, stream>>>(S1, A + 163840, A + 180224, A + 196608,
                                            as_b_in, as_b_in + 128, as_b_in + 256,
                                            np, S0, S4, S3);                  // qs,ks,vs
  sf_attn<<<2048, blk, 0, stream>>>(S0, S4, S3, S1);                          // S1 = self attn
  sf_linM<1, true><<<GL, blk, 0, stream>>>(S1, A + 212992, np, np, as_b_o, nf, nf,
                                           S2, S4, nullptr, nullptr);         // S4 = fused

  sf_heads<<<512, blk, 0, stream>>>(S4, rf_w, rf_b, cf_w, cf_b, out, 0L, 131072L);
}

// Round 10
// 519.908 us; speedup vs baseline: 5.8748x; 1.3489x over previous
//
#include <hip/hip_runtime.h>
#include <hip/hip_bf16.h>

// StockFormer forward, MI355X — bf16 MFMA pipeline v4
// (fused-projection attention, wide-store GEMM epilogues).
// B=4, S=256, N=128, F=64, D=E=128, NH=4, HD=32, BN=512, M=131072. Output f32.
typedef __attribute__((ext_vector_type(8))) short short8v;   // 8 bf16 (4 VGPR)
typedef __attribute__((ext_vector_type(4))) short short4v;   // 4 bf16 (2 VGPR)
typedef __attribute__((ext_vector_type(4))) float f32x4;
typedef __hip_bfloat16 bh;

constexpr long SF_ELEMS = 131072L * 128;   // elements per ws slot (bf16 -> 32 MiB)
#define MFMA16(a, b, c) __builtin_amdgcn_mfma_f32_16x16x32_bf16((a), (b), (c), 0, 0, 0)

__device__ __forceinline__ short bh_bits(float x) {
  bh h = __float2bfloat16(x);
  return *reinterpret_cast<short*>(&h);
}

// Arena (bf16 elems): 0 ta_w_in | 49152 ta_w_o | 65536 pl | 81920 ph | 98304 ac_w_in |
// 147456 ac_w_o | 163840 as_w_in | 212992 as_w_o | 229376 wrep | 278528 end. Then PE f32.

// ---------------------------------------------------------------------------
__global__ __launch_bounds__(256) void sf_wcvt(const float* __restrict__ s0, const float* __restrict__ s1,
                                               const float* __restrict__ s2, const float* __restrict__ s3,
                                               const float* __restrict__ s4, const float* __restrict__ s5,
                                               const float* __restrict__ s6, const float* __restrict__ s7,
                                               const float* __restrict__ cw,
                                               bh* __restrict__ dst) {
  int i = blockIdx.x * 256 + threadIdx.x;
  float v;
  if      (i <  49152) v = s0[i];
  else if (i <  65536) v = s1[i - 49152];
  else if (i <  81920) v = s2[i - 65536];
  else if (i <  98304) v = s3[i - 81920];
  else if (i < 147456) v = s4[i - 98304];
  else if (i < 163840) v = s5[i - 147456];
  else if (i < 212992) v = s6[i - 163840];
  else if (i < 229376) v = s7[i - 212992];
  else if (i < 278528) {                       // conv_w repack: wrep[tap][dch][ic]
    int j = i - 229376;
    int tap = j >> 14, rem = j & 16383;
    v = cw[rem * 3 + tap];
  } else return;
  dst[i] = __float2bfloat16(v);
}

// ---------------------------------------------------------------------------
__global__ __launch_bounds__(256) void sf_pe(float* __restrict__ pe) {
  int i = blockIdx.x * 256 + threadIdx.x;   // [0, 32768)
  int e = i & 127, s = i >> 7;
  int ii = e >> 1;
  float dv = expf(-0.0719557945041855f * (float)(2 * ii));
  float ang = (float)s * dv;
  pe[i] = (e & 1) ? cosf(ang) : sinf(ang);
}

// ---------------------------------------------------------------------------
__global__ __launch_bounds__(256) void sf_build_z(const float* __restrict__ x,
                                                  const float* __restrict__ pe,
                                                  bh* __restrict__ z) {
  long i = (long)blockIdx.x * 256 + threadIdx.x;
  if (i >= SF_ELEMS) return;
  int e = (int)(i & 127);
  int s = (int)((i >> 7) & 255);
  int r = (int)(i >> 15);
  int b = r >> 7, stk = r & 127;
  float val;
  if (e < 64) {
    val = x[(((long)b * 256 + s) * 128 + stk) * 64 + e];
  } else {
    int f = e - 64;
    int t2 = s >> 1;
    float a0 = x[(((long)b * 256 + 2 * t2) * 128 + stk) * 64 + f];
    float a1 = x[(((long)b * 256 + 2 * t2 + 1) * 128 + stk) * 64 + f];
    val = 0.5f * (a0 + a1);
  }
  z[i] = __float2bfloat16(val + pe[s * 128 + e]);
}

// ---------------------------------------------------------------------------
__global__ __launch_bounds__(256) void sf_build_xh(const float* __restrict__ x,
                                                   bh* __restrict__ xh) {
  long i = (long)blockIdx.x * 256 + threadIdx.x;
  if (i >= SF_ELEMS) return;
  int ic = (int)(i & 127);
  int s = (int)((i >> 7) & 255);
  int r = (int)(i >> 15);
  int b = r >> 7, stk = r & 127;
  float val;
  if (ic < 64) {
    val = x[(((long)b * 256 + s) * 128 + stk) * 64 + ic];
  } else {
    int f = ic - 64;
    int t2 = s >> 1;
    float a0 = x[(((long)b * 256 + 2 * t2) * 128 + stk) * 64 + f];
    float a1 = x[(((long)b * 256 + 2 * t2 + 1) * 128 + stk) * 64 + f];
    float d = 0.5f * (a0 - a1);
    val = (s & 1) ? -d : d;
  }
  xh[i] = __float2bfloat16(val);
}

// ---------------------------------------------------------------------------
// MFMA linear, wide-store epilogue: Y[M,128] = X[M,128] @ W^T + b  (ACC: +Prev)
// 4 waves x 32 rows; LDS roundtrip -> 16B coalesced stores (1KB/instr).
// ---------------------------------------------------------------------------
template <bool ACC>
__global__ __launch_bounds__(256) void sf_lin(const bh* __restrict__ X,
                                              const bh* __restrict__ Wb,
                                              const float* __restrict__ bias,
                                              const bh* __restrict__ Prev,
                                              bh* __restrict__ Y) {
  __shared__ bh Lw[4][32][140];
  const int t = threadIdx.x, lane = t & 63, w = t >> 6;
  const int lr = lane & 15, lg = lane >> 4;
  const long R0 = (long)blockIdx.x * 128 + w * 32;
  const f32x4 z4 = {0.f, 0.f, 0.f, 0.f};
  short8v a[2][4];
#pragma unroll
  for (int ks = 0; ks < 4; ++ks) {
    a[0][ks] = *reinterpret_cast<const short8v*>(X + (R0 + lr) * 128 + ks * 32 + lg * 8);
    a[1][ks] = *reinterpret_cast<const short8v*>(X + (R0 + 16 + lr) * 128 + ks * 32 + lg * 8);
  }
  f32x4 acc[2][8];
#pragma unroll
  for (int m = 0; m < 2; ++m)
#pragma unroll
    for (int n = 0; n < 8; ++n) acc[m][n] = z4;
#pragma unroll
  for (int ks = 0; ks < 4; ++ks) {
#pragma unroll
    for (int n = 0; n < 8; ++n) {
      short8v b = *reinterpret_cast<const short8v*>(Wb + (long)(n * 16 + lr) * 128 + ks * 32 + lg * 8);
      acc[0][n] = MFMA16(a[0][ks], b, acc[0][n]);
      acc[1][n] = MFMA16(a[1][ks], b, acc[1][n]);
    }
  }
#pragma unroll
  for (int n = 0; n < 8; ++n) {
    float bv = bias[n * 16 + lr];
#pragma unroll
    for (int m = 0; m < 2; ++m)
#pragma unroll
      for (int r = 0; r < 4; ++r)
        Lw[w][m * 16 + 4 * lg + r][n * 16 + lr] = __float2bfloat16(acc[m][n][r] + bv);
  }
  __syncthreads();
#pragma unroll
  for (int c = 0; c < 8; ++c) {
    int row_l = c * 4 + lg;
    short8v v = *reinterpret_cast<const short8v*>(&Lw[w][row_l][lr * 8]);
    if (ACC) {
      short8v pv = *reinterpret_cast<const short8v*>(Prev + (R0 + row_l) * 128 + lr * 8);
      bh* va = reinterpret_cast<bh*>(&v);
      const bh* pa = reinterpret_cast<const bh*>(&pv);
#pragma unroll
      for (int j = 0; j < 8; ++j)
        va[j] = __float2bfloat16(__bfloat162float(va[j]) + __bfloat162float(pa[j]));
    }
    *reinterpret_cast<short8v*>(Y + (R0 + row_l) * 128 + lr * 8) = v;
  }
}

// ---------------------------------------------------------------------------
// MFMA dilated conv (k=3 pad2 dil2) + ReLU, wide-store epilogue into y_h layout.
// ---------------------------------------------------------------------------
__global__ __launch_bounds__(256) void sf_convm(const bh* __restrict__ Xh,
                                                const bh* __restrict__ Wr,
                                                const float* __restrict__ bias,
                                                bh* __restrict__ Yh) {
  __shared__ bh Lw[4][32][140];
  const int t = threadIdx.x, lane = t & 63, w = t >> 6;
  const int lr = lane & 15, lg = lane >> 4;
  const int bnc = blockIdx.x >> 1;
  const int half = blockIdx.x & 1;
  const int b = bnc >> 7, stk = bnc & 127;
  const int R0 = half * 128 + w * 32;
  const f32x4 z4 = {0.f, 0.f, 0.f, 0.f};
  const short8v zf = {0, 0, 0, 0, 0, 0, 0, 0};
  f32x4 acc[2][8];
#pragma unroll
  for (int m = 0; m < 2; ++m)
#pragma unroll
    for (int n = 0; n < 8; ++n) acc[m][n] = z4;
#pragma unroll
  for (int tap = 0; tap < 3; ++tap) {
    const int shift = 2 * tap - 2;
#pragma unroll
    for (int ks = 0; ks < 4; ++ks) {
      int s0 = R0 + lr + shift;
      int s1 = s0 + 16;
      short8v a0 = zf, a1 = zf;
      if ((unsigned)s0 < 256u)
        a0 = *reinterpret_cast<const short8v*>(Xh + ((long)bnc * 256 + s0) * 128 + ks * 32 + lg * 8);
      if ((unsigned)s1 < 256u)
        a1 = *reinterpret_cast<const short8v*>(Xh + ((long)bnc * 256 + s1) * 128 + ks * 32 + lg * 8);
#pragma unroll
      for (int n = 0; n < 8; ++n) {
        short8v bb = *reinterpret_cast<const short8v*>(Wr + (long)tap * 16384 + (long)(n * 16 + lr) * 128 + ks * 32 + lg * 8);
        acc[0][n] = MFMA16(a0, bb, acc[0][n]);
        acc[1][n] = MFMA16(a1, bb, acc[1][n]);
      }
    }
  }
#pragma unroll
  for (int n = 0; n < 8; ++n) {
    float bv = bias[n * 16 + lr];
#pragma unroll
    for (int m = 0; m < 2; ++m)
#pragma unroll
      for (int r = 0; r < 4; ++r)
        Lw[w][m * 16 + 4 * lg + r][n * 16 + lr] = __float2bfloat16(fmaxf(acc[m][n][r] + bv, 0.f));
  }
  __syncthreads();
#pragma unroll
  for (int c = 0; c < 8; ++c) {
    int row_l = c * 4 + lg;
    int sc = R0 + row_l;
    int rp = b * 128 + (sc >> 1);
    int sp = ((sc & 1) << 7) + stk;
    short8v v = *reinterpret_cast<const short8v*>(&Lw[w][row_l][lr * 8]);
    *reinterpret_cast<short8v*>(Yh + ((long)rp * 256 + sp) * 128 + lr * 8) = v;
  }
}

// ---------------------------------------------------------------------------
// Fused-projection MFMA attention: block=(bn,h), 4 waves.
// Projection phase: Q/K/V head-slices computed in-block (Q->Qs per-wave LDS,
// K->Ks [krow][d], V->Vt [d][krow] via b64 packs). One barrier, then r9's
// no-max exp attention (S^T = MFMA(K,Q), lane-local row-sums).
// ---------------------------------------------------------------------------
__global__ __launch_bounds__(256) void sf_attnp(const bh* Qsrc, const bh* KVsrc,
                                                const bh* __restrict__ Win,
                                                const float* __restrict__ bin,
                                                bh* __restrict__ O) {
  __shared__ bh Ks[256][36];      // 18.0 KB (krow, d)
  __shared__ bh Vt[32][260];      // 16.3 KB (d, krow)
  __shared__ bh Qs[4][64][36];    // 18.0 KB per-wave (qrow, d)
  __shared__ bh Pl[4][16][72];    //  9.0 KB
  const int t = threadIdx.x, lane = t & 63, w = t >> 6;
  const int lr = lane & 15, lg = lane >> 4;
  const int bn = blockIdx.x >> 2, h = blockIdx.x & 3;
  const long R0 = (long)bn * 256;
  const int ch = h * 32;
  const f32x4 z4 = {0.f, 0.f, 0.f, 0.f};
  // ---- Q projection (64 rows of Qsrc per wave) ----
  {
    short8v wq[2][4];
#pragma unroll
    for (int n = 0; n < 2; ++n)
#pragma unroll
      for (int ks = 0; ks < 4; ++ks)
        wq[n][ks] = *reinterpret_cast<const short8v*>(Win + (long)(ch + n * 16 + lr) * 128 + ks * 32 + lg * 8);
#pragma unroll
    for (int m2 = 0; m2 < 4; ++m2) {
      short8v asv[4];
#pragma unroll
      for (int ks = 0; ks < 4; ++ks)
        asv[ks] = *reinterpret_cast<const short8v*>(Qsrc + (R0 + w * 64 + m2 * 16 + lr) * 128 + ks * 32 + lg * 8);
#pragma unroll
      for (int n = 0; n < 2; ++n) {
        f32x4 acc = z4;
#pragma unroll
        for (int ks = 0; ks < 4; ++ks) acc = MFMA16(asv[ks], wq[n][ks], acc);
        float bb = bin[ch + n * 16 + lr];
#pragma unroll
        for (int r = 0; r < 4; ++r)
          Qs[w][m2 * 16 + 4 * lg + r][n * 16 + lr] = __float2bfloat16(acc[r] + bb);
      }
    }
  }
  // ---- K,V projection (64 rows of KVsrc per wave; shared A-frags) ----
  {
    short8v wk[2][4], wv[2][4];
#pragma unroll
    for (int n = 0; n < 2; ++n)
#pragma unroll
      for (int ks = 0; ks < 4; ++ks) {
        wk[n][ks] = *reinterpret_cast<const short8v*>(Win + (long)(128 + ch + n * 16 + lr) * 128 + ks * 32 + lg * 8);
        wv[n][ks] = *reinterpret_cast<const short8v*>(Win + (long)(256 + ch + n * 16 + lr) * 128 + ks * 32 + lg * 8);
      }
#pragma unroll
    for (int m2 = 0; m2 < 4; ++m2) {
      short8v asv[4];
#pragma unroll
      for (int ks = 0; ks < 4; ++ks)
        asv[ks] = *reinterpret_cast<const short8v*>(KVsrc + (R0 + w * 64 + m2 * 16 + lr) * 128 + ks * 32 + lg * 8);
#pragma unroll
      for (int n = 0; n < 2; ++n) {
        f32x4 ak = z4, av = z4;
#pragma unroll
        for (int ks = 0; ks < 4; ++ks) {
          ak = MFMA16(asv[ks], wk[n][ks], ak);
          av = MFMA16(asv[ks], wv[n][ks], av);
        }
        float bk = bin[128 + ch + n * 16 + lr];
        float bv = bin[256 + ch + n * 16 + lr];
#pragma unroll
        for (int r = 0; r < 4; ++r)
          Ks[w * 64 + m2 * 16 + 4 * lg + r][n * 16 + lr] = __float2bfloat16(ak[r] + bk);
        short4v pv;
#pragma unroll
        for (int r = 0; r < 4; ++r) pv[r] = bh_bits(av[r] + bv);
        *reinterpret_cast<short4v*>(&Vt[n * 16 + lr][w * 64 + m2 * 16 + 4 * lg]) = pv;
      }
    }
  }
  __syncthreads();
  // ---- attention (r9 structure, fully-staged K/V, no inner barriers) ----
  const float sc = 0.17677669529663687f;  // 1/sqrt(32)
  short8v aq[4];
#pragma unroll
  for (int mt = 0; mt < 4; ++mt)
    aq[mt] = *reinterpret_cast<const short8v*>(&Qs[w][mt * 16 + lr][lg * 8]);
  f32x4 Oacc[4][2];
  float psum[4] = {0.f, 0.f, 0.f, 0.f};
#pragma unroll
  for (int mt = 0; mt < 4; ++mt) { Oacc[mt][0] = z4; Oacc[mt][1] = z4; }
#pragma unroll
  for (int kt = 0; kt < 4; ++kt) {
    short8v bvf[2][2];
#pragma unroll
    for (int dt = 0; dt < 2; ++dt)
#pragma unroll
      for (int ks = 0; ks < 2; ++ks)
        bvf[dt][ks] = *reinterpret_cast<const short8v*>(&Vt[dt * 16 + lr][kt * 64 + ks * 32 + lg * 8]);
#pragma unroll
    for (int mt = 0; mt < 4; ++mt) {
      f32x4 st[4];
#pragma unroll
      for (int nt = 0; nt < 4; ++nt) {
        short8v bk = *reinterpret_cast<const short8v*>(&Ks[kt * 64 + nt * 16 + lr][lg * 8]);
        st[nt] = MFMA16(bk, aq[mt], z4);     // S^T = K·Q^T
      }
      float ps = 0.f;
#pragma unroll
      for (int nt = 0; nt < 4; ++nt) {
        float p0 = __expf(st[nt][0] * sc);
        float p1 = __expf(st[nt][1] * sc);
        float p2 = __expf(st[nt][2] * sc);
        float p3 = __expf(st[nt][3] * sc);
        ps += (p0 + p1) + (p2 + p3);
        short4v pk;
        pk[0] = bh_bits(p0); pk[1] = bh_bits(p1); pk[2] = bh_bits(p2); pk[3] = bh_bits(p3);
        *reinterpret_cast<short4v*>(&Pl[w][lr][nt * 16 + 4 * lg]) = pk;
      }
      psum[mt] += ps;
#pragma unroll
      for (int ks = 0; ks < 2; ++ks) {
        short8v ap = *reinterpret_cast<const short8v*>(&Pl[w][lr][ks * 32 + lg * 8]);
        Oacc[mt][0] = MFMA16(ap, bvf[0][ks], Oacc[mt][0]);
        Oacc[mt][1] = MFMA16(ap, bvf[1][ks], Oacc[mt][1]);
      }
    }
  }
#pragma unroll
  for (int mt = 0; mt < 4; ++mt) {
    float ps = psum[mt];
    ps += __shfl_xor(ps, 16, 64);
    ps += __shfl_xor(ps, 32, 64);
    float inv = 1.f / ps;
#pragma unroll
    for (int r = 0; r < 4; ++r) {
      float invr = __shfl(inv, 4 * lg + r, 64);
      long row = R0 + w * 64 + mt * 16 + 4 * lg + r;
      O[row * 128 + ch + lr]      = __float2bfloat16(Oacc[mt][0][r] * invr);
      O[row * 128 + ch + 16 + lr] = __float2bfloat16(Oacc[mt][1][r] * invr);
    }
  }
}

// ---------------------------------------------------------------------------
// heads: reg = X@rw^T+rb ; cla = softmax2(X@cw^T+cb); bf16 in, f32 out (idx=row)
// ---------------------------------------------------------------------------
__global__ __launch_bounds__(256) void sf_heads(const bh* __restrict__ X,
                                                const float* __restrict__ rw,
                                                const float* __restrict__ rb,
                                                const float* __restrict__ cw,
                                                const float* __restrict__ cb,
                                                float* __restrict__ out,
                                                long off_reg, long off_cla) {
  __shared__ float w0[128], w1[128], w2[128];
  const int t = threadIdx.x;
  if (t < 128) { w0[t] = rw[t]; w1[t] = cw[t]; w2[t] = cw[128 + t]; }
  __syncthreads();
  long row = (long)blockIdx.x * 256 + t;
  const bh* xr = X + row * 128;
  float d0 = 0.f, d1 = 0.f, d2 = 0.f;
#pragma unroll 4
  for (int j = 0; j < 128; j += 8) {
    short8v v8 = *reinterpret_cast<const short8v*>(xr + j);
    const bh* vv = reinterpret_cast<const bh*>(&v8);
#pragma unroll
    for (int k = 0; k < 8; ++k) {
      float f = __bfloat162float(vv[k]);
      d0 = fmaf(f, w0[j + k], d0);
      d1 = fmaf(f, w1[j + k], d1);
      d2 = fmaf(f, w2[j + k], d2);
    }
  }
  d0 += rb[0]; d1 += cb[0]; d2 += cb[1];
  float mx = fmaxf(d1, d2);
  float e1 = expf(d1 - mx), e2 = expf(d2 - mx);
  float inv = 1.f / (e1 + e2);
  out[off_reg + row] = d0;
  out[off_cla + row * 2] = e1 * inv;
  out[off_cla + row * 2 + 1] = e2 * inv;
}

// ---------------------------------------------------------------------------
extern "C" void kernel_launch(void* const* d_in, const int* in_sizes, int n_in,
                              void* d_out, int out_size, void* d_ws, size_t ws_size,
                              hipStream_t stream) {
  (void)in_sizes; (void)n_in; (void)out_size; (void)ws_size;
  const float* x       = (const float*)d_in[0];
  const float* ta_w_in = (const float*)d_in[2];
  const float* ta_b_in = (const float*)d_in[3];
  const float* ta_w_o  = (const float*)d_in[4];
  const float* ta_b_o  = (const float*)d_in[5];
  const float* conv_w  = (const float*)d_in[6];
  const float* conv_b  = (const float*)d_in[7];
  const float* pl_w    = (const float*)d_in[8];
  const float* pl_b    = (const float*)d_in[9];
  const float* ph_w    = (const float*)d_in[10];
  const float* ph_b    = (const float*)d_in[11];
  const float* as_w_in = (const float*)d_in[12];
  const float* as_b_in = (const float*)d_in[13];
  const float* as_w_o  = (const float*)d_in[14];
  const float* as_b_o  = (const float*)d_in[15];
  const float* ac_w_in = (const float*)d_in[16];
  const float* ac_b_in = (const float*)d_in[17];
  const float* ac_w_o  = (const float*)d_in[18];
  const float* ac_b_o  = (const float*)d_in[19];
  const float* rl_w    = (const float*)d_in[20];
  const float* rl_b    = (const float*)d_in[21];
  const float* cl_w    = (const float*)d_in[22];
  const float* cl_b    = (const float*)d_in[23];
  const float* rf_w    = (const float*)d_in[24];
  const float* rf_b    = (const float*)d_in[25];
  const float* cf_w    = (const float*)d_in[26];
  const float* cf_b    = (const float*)d_in[27];
  float* out = (float*)d_out;

  bh* S0 = (bh*)d_ws;
  bh* S1 = S0 + SF_ELEMS;
  bh* S2 = S1 + SF_ELEMS;
  bh* S3 = S2 + SF_ELEMS;
  bh* S4 = S3 + SF_ELEMS;
  bh* A  = S4 + SF_ELEMS;             // bf16 arena (278528)
  float* PE = (float*)(A + 278528);   // 32768 f32

  dim3 blk(256);
  const int GZ = (int)(SF_ELEMS / 256);
  const int GL = 1024;                // 131072 / 128
  const bh* np = nullptr;

  sf_wcvt<<<1088, blk, 0, stream>>>(ta_w_in, ta_w_o, pl_w, ph_w, ac_w_in, ac_w_o,
                                    as_w_in, as_w_o, conv_w, A);
  sf_pe<<<128, blk, 0, stream>>>(PE);

  // ---- encoder ----
  sf_build_z<<<GZ, blk, 0, stream>>>(x, PE, S0);                               // S0 = z
  sf_attnp<<<2048, blk, 0, stream>>>(S0, S0, A, ta_b_in, S1);                  // S1 = enc attn
  sf_lin<false><<<GL, blk, 0, stream>>>(S1, A + 49152, ta_b_o, np, S2);        // S2 = y_l
  sf_build_xh<<<GZ, blk, 0, stream>>>(x, S3);                                  // S3 = xh
  sf_convm<<<1024, blk, 0, stream>>>(S3, A + 229376, conv_b, S4);              // S4 = y_h

  // ---- decoder projections + aux heads ----
  sf_lin<false><<<GL, blk, 0, stream>>>(S4, A + 81920, ph_b, np, S0);          // S0 = k_h
  sf_lin<false><<<GL, blk, 0, stream>>>(S2, A + 65536, pl_b, np, S1);          // S1 = q_l
  sf_lin<false><<<GL, blk, 0, stream>>>(S1, A + 65536, pl_b, np, S3);          // S3 = y_l2
  sf_heads<<<512, blk, 0, stream>>>(S3, rl_w, rl_b, cl_w, cl_b, out, 393216L, 524288L);

  // ---- cross attention (q = q_l, k/v = k_h) ----
  sf_attnp<<<2048, blk, 0, stream>>>(S1, S0, A + 98304, ac_b_in, S2);          // S2 = cross attn
  sf_lin<false><<<GL, blk, 0, stream>>>(S2, A + 147456, ac_b_o, np, S3);       // S3 = a_cross

  // ---- self attention (q/k/v = q_l) ----
  sf_attnp<<<2048, blk, 0, stream>>>(S1, S1, A + 163840, as_b_in, S4);         // S4 = self attn
  sf_lin<true><<<GL, blk, 0, stream>>>(S4, A + 212992, as_b_o, S3, S2);        // S2 = fused

  sf_heads<<<512, blk, 0, stream>>>(S2, rf_w, rf_b, cf_w, cf_b, out, 0L, 131072L);
}

// Round 11
// 471.836 us; speedup vs baseline: 6.4733x; 1.1019x over previous
//
#include <hip/hip_runtime.h>
#include <hip/hip_bf16.h>

// StockFormer forward, MI355X — bf16 MFMA pipeline v5
// (3-block/CU fused-proj attention + exp2 fold; GEMM-chain fusion; fused heads).
// B=4, S=256, N=128, F=64, D=E=128, NH=4, HD=32, BN=512, M=131072. Output f32.
typedef __attribute__((ext_vector_type(8))) short short8v;   // 8 bf16 (4 VGPR)
typedef __attribute__((ext_vector_type(4))) short short4v;   // 4 bf16 (2 VGPR)
typedef __attribute__((ext_vector_type(4))) float f32x4;
typedef __hip_bfloat16 bh;

constexpr long SF_ELEMS = 131072L * 128;   // elements per ws slot (bf16 -> 32 MiB)
#define MFMA16(a, b, c) __builtin_amdgcn_mfma_f32_16x16x32_bf16((a), (b), (c), 0, 0, 0)

__device__ __forceinline__ short bh_bits(float x) {
  bh h = __float2bfloat16(x);
  return *reinterpret_cast<short*>(&h);
}

// Arena (bf16 elems): 0 ta_w_in | 49152 ta_w_o | 65536 pl | 81920 ph | 98304 ac_w_in |
// 147456 ac_w_o | 163840 as_w_in | 212992 as_w_o | 229376 wrep | 278528 end. Then PE f32.

// ---------------------------------------------------------------------------
__global__ __launch_bounds__(256) void sf_wcvt(const float* __restrict__ s0, const float* __restrict__ s1,
                                               const float* __restrict__ s2, const float* __restrict__ s3,
                                               const float* __restrict__ s4, const float* __restrict__ s5,
                                               const float* __restrict__ s6, const float* __restrict__ s7,
                                               const float* __restrict__ cw,
                                               bh* __restrict__ dst) {
  int i = blockIdx.x * 256 + threadIdx.x;
  float v;
  if      (i <  49152) v = s0[i];
  else if (i <  65536) v = s1[i - 49152];
  else if (i <  81920) v = s2[i - 65536];
  else if (i <  98304) v = s3[i - 81920];
  else if (i < 147456) v = s4[i - 98304];
  else if (i < 163840) v = s5[i - 147456];
  else if (i < 212992) v = s6[i - 163840];
  else if (i < 229376) v = s7[i - 212992];
  else if (i < 278528) {                       // conv_w repack: wrep[tap][dch][ic]
    int j = i - 229376;
    int tap = j >> 14, rem = j & 16383;
    v = cw[rem * 3 + tap];
  } else return;
  dst[i] = __float2bfloat16(v);
}

// ---------------------------------------------------------------------------
__global__ __launch_bounds__(256) void sf_pe(float* __restrict__ pe) {
  int i = blockIdx.x * 256 + threadIdx.x;   // [0, 32768)
  int e = i & 127, s = i >> 7;
  int ii = e >> 1;
  float dv = expf(-0.0719557945041855f * (float)(2 * ii));
  float ang = (float)s * dv;
  pe[i] = (e & 1) ? cosf(ang) : sinf(ang);
}

// ---------------------------------------------------------------------------
// z (xl_cat + PE) and xh (xh_cat) in one pass over x.
// ---------------------------------------------------------------------------
__global__ __launch_bounds__(256) void sf_buildzx(const float* __restrict__ x,
                                                  const float* __restrict__ pe,
                                                  bh* __restrict__ z,
                                                  bh* __restrict__ xh) {
  long i = (long)blockIdx.x * 256 + threadIdx.x;
  if (i >= SF_ELEMS) return;
  int e = (int)(i & 127);
  int s = (int)((i >> 7) & 255);
  int r = (int)(i >> 15);
  int b = r >> 7, stk = r & 127;
  float zv, hv;
  if (e < 64) {
    float val = x[(((long)b * 256 + s) * 128 + stk) * 64 + e];
    zv = val; hv = val;
  } else {
    int f = e - 64;
    int t2 = s >> 1;
    float a0 = x[(((long)b * 256 + 2 * t2) * 128 + stk) * 64 + f];
    float a1 = x[(((long)b * 256 + 2 * t2 + 1) * 128 + stk) * 64 + f];
    zv = 0.5f * (a0 + a1);
    float d = 0.5f * (a0 - a1);
    hv = (s & 1) ? -d : d;
  }
  z[i] = __float2bfloat16(zv + pe[s * 128 + e]);
  xh[i] = __float2bfloat16(hv);
}

// ---------------------------------------------------------------------------
// MFMA linear, wide-store epilogue: Y[M,128] = X[M,128] @ W^T + b
// ---------------------------------------------------------------------------
__global__ __launch_bounds__(256) void sf_lin(const bh* __restrict__ X,
                                              const bh* __restrict__ Wb,
                                              const float* __restrict__ bias,
                                              bh* __restrict__ Y) {
  __shared__ bh Lw[4][32][140];
  const int t = threadIdx.x, lane = t & 63, w = t >> 6;
  const int lr = lane & 15, lg = lane >> 4;
  const long R0 = (long)blockIdx.x * 128 + w * 32;
  const f32x4 z4 = {0.f, 0.f, 0.f, 0.f};
  short8v a[2][4];
#pragma unroll
  for (int ks = 0; ks < 4; ++ks) {
    a[0][ks] = *reinterpret_cast<const short8v*>(X + (R0 + lr) * 128 + ks * 32 + lg * 8);
    a[1][ks] = *reinterpret_cast<const short8v*>(X + (R0 + 16 + lr) * 128 + ks * 32 + lg * 8);
  }
  f32x4 acc[2][8];
#pragma unroll
  for (int m = 0; m < 2; ++m)
#pragma unroll
    for (int n = 0; n < 8; ++n) acc[m][n] = z4;
#pragma unroll
  for (int ks = 0; ks < 4; ++ks) {
#pragma unroll
    for (int n = 0; n < 8; ++n) {
      short8v b = *reinterpret_cast<const short8v*>(Wb + (long)(n * 16 + lr) * 128 + ks * 32 + lg * 8);
      acc[0][n] = MFMA16(a[0][ks], b, acc[0][n]);
      acc[1][n] = MFMA16(a[1][ks], b, acc[1][n]);
    }
  }
#pragma unroll
  for (int n = 0; n < 8; ++n) {
    float bv = bias[n * 16 + lr];
#pragma unroll
    for (int m = 0; m < 2; ++m)
#pragma unroll
      for (int r = 0; r < 4; ++r)
        Lw[w][m * 16 + 4 * lg + r][n * 16 + lr] = __float2bfloat16(acc[m][n][r] + bv);
  }
#pragma unroll
  for (int c = 0; c < 8; ++c) {
    int row_l = c * 4 + lg;
    short8v v = *reinterpret_cast<const short8v*>(&Lw[w][row_l][lr * 8]);
    *reinterpret_cast<short8v*>(Y + (R0 + row_l) * 128 + lr * 8) = v;
  }
}

// ---------------------------------------------------------------------------
// MFMA dilated conv (k=3 pad2 dil2) + ReLU, wide-store epilogue into y_h layout.
// ---------------------------------------------------------------------------
__global__ __launch_bounds__(256) void sf_convm(const bh* __restrict__ Xh,
                                                const bh* __restrict__ Wr,
                                                const float* __restrict__ bias,
                                                bh* __restrict__ Yh) {
  __shared__ bh Lw[4][32][140];
  const int t = threadIdx.x, lane = t & 63, w = t >> 6;
  const int lr = lane & 15, lg = lane >> 4;
  const int bnc = blockIdx.x >> 1;
  const int half = blockIdx.x & 1;
  const int b = bnc >> 7, stk = bnc & 127;
  const int R0 = half * 128 + w * 32;
  const f32x4 z4 = {0.f, 0.f, 0.f, 0.f};
  const short8v zf = {0, 0, 0, 0, 0, 0, 0, 0};
  f32x4 acc[2][8];
#pragma unroll
  for (int m = 0; m < 2; ++m)
#pragma unroll
    for (int n = 0; n < 8; ++n) acc[m][n] = z4;
#pragma unroll
  for (int tap = 0; tap < 3; ++tap) {
    const int shift = 2 * tap - 2;
#pragma unroll
    for (int ks = 0; ks < 4; ++ks) {
      int s0 = R0 + lr + shift;
      int s1 = s0 + 16;
      short8v a0 = zf, a1 = zf;
      if ((unsigned)s0 < 256u)
        a0 = *reinterpret_cast<const short8v*>(Xh + ((long)bnc * 256 + s0) * 128 + ks * 32 + lg * 8);
      if ((unsigned)s1 < 256u)
        a1 = *reinterpret_cast<const short8v*>(Xh + ((long)bnc * 256 + s1) * 128 + ks * 32 + lg * 8);
#pragma unroll
      for (int n = 0; n < 8; ++n) {
        short8v bb = *reinterpret_cast<const short8v*>(Wr + (long)tap * 16384 + (long)(n * 16 + lr) * 128 + ks * 32 + lg * 8);
        acc[0][n] = MFMA16(a0, bb, acc[0][n]);
        acc[1][n] = MFMA16(a1, bb, acc[1][n]);
      }
    }
  }
#pragma unroll
  for (int n = 0; n < 8; ++n) {
    float bv = bias[n * 16 + lr];
#pragma unroll
    for (int m = 0; m < 2; ++m)
#pragma unroll
      for (int r = 0; r < 4; ++r)
        Lw[w][m * 16 + 4 * lg + r][n * 16 + lr] = __float2bfloat16(fmaxf(acc[m][n][r] + bv, 0.f));
  }
#pragma unroll
  for (int c = 0; c < 8; ++c) {
    int row_l = c * 4 + lg;
    int sc = R0 + row_l;
    int rp = b * 128 + (sc >> 1);
    int sp = ((sc & 1) << 7) + stk;
    short8v v = *reinterpret_cast<const short8v*>(&Lw[w][row_l][lr * 8]);
    *reinterpret_cast<short8v*>(Yh + ((long)rp * 256 + sp) * 128 + lr * 8) = v;
  }
}

// ---------------------------------------------------------------------------
// Fused-projection MFMA attention v5: P-tile overlaid on Q staging (52.3 KB LDS
// -> 3 blocks/CU); 1/sqrt(32)*log2(e) folded into Q store; exp2f scores.
// ---------------------------------------------------------------------------
__global__ __launch_bounds__(256) void sf_attnp(const bh* Qsrc, const bh* KVsrc,
                                                const bh* __restrict__ Win,
                                                const float* __restrict__ bin,
                                                bh* __restrict__ O) {
  __shared__ bh Ks[256][36];      // 18.0 KB (krow, d)
  __shared__ bh Vt[32][260];      // 16.3 KB (d, krow)
  __shared__ bh QP[4][64][36];    // 18.0 KB per-wave: Q staging, then P tile
  const int t = threadIdx.x, lane = t & 63, w = t >> 6;
  const int lr = lane & 15, lg = lane >> 4;
  const int bn = blockIdx.x >> 2, h = blockIdx.x & 3;
  const long R0 = (long)bn * 256;
  const int ch = h * 32;
  const f32x4 z4 = {0.f, 0.f, 0.f, 0.f};
  const float SC2 = 0.2550351f;   // (1/sqrt(32)) * log2(e), folded into Q
  // ---- Q projection (64 rows per wave), scaled by SC2 ----
  {
    short8v wq[2][4];
#pragma unroll
    for (int n = 0; n < 2; ++n)
#pragma unroll
      for (int ks = 0; ks < 4; ++ks)
        wq[n][ks] = *reinterpret_cast<const short8v*>(Win + (long)(ch + n * 16 + lr) * 128 + ks * 32 + lg * 8);
#pragma unroll
    for (int m2 = 0; m2 < 4; ++m2) {
      short8v asv[4];
#pragma unroll
      for (int ks = 0; ks < 4; ++ks)
        asv[ks] = *reinterpret_cast<const short8v*>(Qsrc + (R0 + w * 64 + m2 * 16 + lr) * 128 + ks * 32 + lg * 8);
#pragma unroll
      for (int n = 0; n < 2; ++n) {
        f32x4 acc = z4;
#pragma unroll
        for (int ks = 0; ks < 4; ++ks) acc = MFMA16(asv[ks], wq[n][ks], acc);
        float bb = bin[ch + n * 16 + lr];
#pragma unroll
        for (int r = 0; r < 4; ++r)
          QP[w][m2 * 16 + 4 * lg + r][n * 16 + lr] = __float2bfloat16((acc[r] + bb) * SC2);
      }
    }
  }
  // ---- K,V projection (64 rows per wave; shared A-frags) ----
  {
    short8v wk[2][4], wv[2][4];
#pragma unroll
    for (int n = 0; n < 2; ++n)
#pragma unroll
      for (int ks = 0; ks < 4; ++ks) {
        wk[n][ks] = *reinterpret_cast<const short8v*>(Win + (long)(128 + ch + n * 16 + lr) * 128 + ks * 32 + lg * 8);
        wv[n][ks] = *reinterpret_cast<const short8v*>(Win + (long)(256 + ch + n * 16 + lr) * 128 + ks * 32 + lg * 8);
      }
#pragma unroll
    for (int m2 = 0; m2 < 4; ++m2) {
      short8v asv[4];
#pragma unroll
      for (int ks = 0; ks < 4; ++ks)
        asv[ks] = *reinterpret_cast<const short8v*>(KVsrc + (R0 + w * 64 + m2 * 16 + lr) * 128 + ks * 32 + lg * 8);
#pragma unroll
      for (int n = 0; n < 2; ++n) {
        f32x4 ak = z4, av = z4;
#pragma unroll
        for (int ks = 0; ks < 4; ++ks) {
          ak = MFMA16(asv[ks], wk[n][ks], ak);
          av = MFMA16(asv[ks], wv[n][ks], av);
        }
        float bk = bin[128 + ch + n * 16 + lr];
        float bv = bin[256 + ch + n * 16 + lr];
#pragma unroll
        for (int r = 0; r < 4; ++r)
          Ks[w * 64 + m2 * 16 + 4 * lg + r][n * 16 + lr] = __float2bfloat16(ak[r] + bk);
        short4v pv;
#pragma unroll
        for (int r = 0; r < 4; ++r) pv[r] = bh_bits(av[r] + bv);
        *reinterpret_cast<short4v*>(&Vt[n * 16 + lr][w * 64 + m2 * 16 + 4 * lg]) = pv;
      }
    }
  }
  __syncthreads();
  // ---- attention: aq from QP (then QP[w] becomes the per-wave P tile) ----
  short8v aq[4];
#pragma unroll
  for (int mt = 0; mt < 4; ++mt)
    aq[mt] = *reinterpret_cast<const short8v*>(&QP[w][mt * 16 + lr][lg * 8]);
  bh* plp = &QP[w][0][0];   // P tile: (lr, c) at plp[lr*72 + c], wave-local
  f32x4 Oacc[4][2];
  float psum[4] = {0.f, 0.f, 0.f, 0.f};
#pragma unroll
  for (int mt = 0; mt < 4; ++mt) { Oacc[mt][0] = z4; Oacc[mt][1] = z4; }
#pragma unroll
  for (int kt = 0; kt < 4; ++kt) {
    short8v bvf[2][2];
#pragma unroll
    for (int dt = 0; dt < 2; ++dt)
#pragma unroll
      for (int ks = 0; ks < 2; ++ks)
        bvf[dt][ks] = *reinterpret_cast<const short8v*>(&Vt[dt * 16 + lr][kt * 64 + ks * 32 + lg * 8]);
#pragma unroll
    for (int mt = 0; mt < 4; ++mt) {
      f32x4 st[4];
#pragma unroll
      for (int nt = 0; nt < 4; ++nt) {
        short8v bk = *reinterpret_cast<const short8v*>(&Ks[kt * 64 + nt * 16 + lr][lg * 8]);
        st[nt] = MFMA16(bk, aq[mt], z4);     // S^T·SC2 = K·(Q*SC2)^T
      }
      float ps = 0.f;
#pragma unroll
      for (int nt = 0; nt < 4; ++nt) {
        float p0 = exp2f(st[nt][0]);
        float p1 = exp2f(st[nt][1]);
        float p2 = exp2f(st[nt][2]);
        float p3 = exp2f(st[nt][3]);
        ps += (p0 + p1) + (p2 + p3);
        short4v pk;
        pk[0] = bh_bits(p0); pk[1] = bh_bits(p1); pk[2] = bh_bits(p2); pk[3] = bh_bits(p3);
        *reinterpret_cast<short4v*>(&plp[lr * 72 + nt * 16 + 4 * lg]) = pk;
      }
      psum[mt] += ps;
#pragma unroll
      for (int ks = 0; ks < 2; ++ks) {
        short8v ap = *reinterpret_cast<const short8v*>(&plp[lr * 72 + ks * 32 + lg * 8]);
        Oacc[mt][0] = MFMA16(ap, bvf[0][ks], Oacc[mt][0]);
        Oacc[mt][1] = MFMA16(ap, bvf[1][ks], Oacc[mt][1]);
      }
    }
  }
#pragma unroll
  for (int mt = 0; mt < 4; ++mt) {
    float ps = psum[mt];
    ps += __shfl_xor(ps, 16, 64);
    ps += __shfl_xor(ps, 32, 64);
    float inv = 1.f / ps;
#pragma unroll
    for (int r = 0; r < 4; ++r) {
      float invr = __shfl(inv, 4 * lg + r, 64);
      long row = R0 + w * 64 + mt * 16 + 4 * lg + r;
      O[row * 128 + ch + lr]      = __float2bfloat16(Oacc[mt][0][r] * invr);
      O[row * 128 + ch + 16 + lr] = __float2bfloat16(Oacc[mt][1][r] * invr);
    }
  }
}

// ---------------------------------------------------------------------------
// Fused decoder chain: X -> (Wo) y_l -> (pl) q_l [stored] -> (pl) y_l2 -> heads.
// All stages chained through per-wave epilogue LDS tile (in-order DS per wave).
// ---------------------------------------------------------------------------
__global__ __launch_bounds__(256) void sf_encdec(const bh* __restrict__ X,
                                                 const bh* __restrict__ Wo, const float* __restrict__ bo,
                                                 const bh* __restrict__ Wpl, const float* __restrict__ bpl,
                                                 const float* __restrict__ rw, const float* __restrict__ rb,
                                                 const float* __restrict__ cw, const float* __restrict__ cb,
                                                 bh* __restrict__ Yq, float* __restrict__ out,
                                                 long off_reg, long off_cla) {
  __shared__ bh Lw[4][32][140];
  __shared__ float hw[3][128];
  const int t = threadIdx.x, lane = t & 63, w = t >> 6;
  const int lr = lane & 15, lg = lane >> 4;
  const long R0 = (long)blockIdx.x * 128 + w * 32;
  const f32x4 z4 = {0.f, 0.f, 0.f, 0.f};
  if (t < 128) { hw[0][t] = rw[t]; hw[1][t] = cw[t]; hw[2][t] = cw[128 + t]; }
  // ---- stage A: y_l = X·Wo^T + bo ----
  {
    short8v a[2][4];
#pragma unroll
    for (int ks = 0; ks < 4; ++ks) {
      a[0][ks] = *reinterpret_cast<const short8v*>(X + (R0 + lr) * 128 + ks * 32 + lg * 8);
      a[1][ks] = *reinterpret_cast<const short8v*>(X + (R0 + 16 + lr) * 128 + ks * 32 + lg * 8);
    }
    f32x4 acc[2][8];
#pragma unroll
    for (int m = 0; m < 2; ++m)
#pragma unroll
      for (int n = 0; n < 8; ++n) acc[m][n] = z4;
#pragma unroll
    for (int ks = 0; ks < 4; ++ks)
#pragma unroll
      for (int n = 0; n < 8; ++n) {
        short8v b = *reinterpret_cast<const short8v*>(Wo + (long)(n * 16 + lr) * 128 + ks * 32 + lg * 8);
        acc[0][n] = MFMA16(a[0][ks], b, acc[0][n]);
        acc[1][n] = MFMA16(a[1][ks], b, acc[1][n]);
      }
#pragma unroll
    for (int n = 0; n < 8; ++n) {
      float bv = bo[n * 16 + lr];
#pragma unroll
      for (int m = 0; m < 2; ++m)
#pragma unroll
        for (int r = 0; r < 4; ++r)
          Lw[w][m * 16 + 4 * lg + r][n * 16 + lr] = __float2bfloat16(acc[m][n][r] + bv);
    }
  }
  // ---- stage B: q_l = y_l·pl^T + bpl (from Lw), store to Yq + Lw ----
  // ---- stage C: y_l2 = q_l·pl^T + bpl (from Lw), to Lw ----
#pragma unroll
  for (int stage = 0; stage < 2; ++stage) {
    short8v a[2][4];
#pragma unroll
    for (int ks = 0; ks < 4; ++ks) {
      a[0][ks] = *reinterpret_cast<const short8v*>(&Lw[w][lr][ks * 32 + lg * 8]);
      a[1][ks] = *reinterpret_cast<const short8v*>(&Lw[w][16 + lr][ks * 32 + lg * 8]);
    }
    f32x4 acc[2][8];
#pragma unroll
    for (int m = 0; m < 2; ++m)
#pragma unroll
      for (int n = 0; n < 8; ++n) acc[m][n] = z4;
#pragma unroll
    for (int ks = 0; ks < 4; ++ks)
#pragma unroll
      for (int n = 0; n < 8; ++n) {
        short8v b = *reinterpret_cast<const short8v*>(Wpl + (long)(n * 16 + lr) * 128 + ks * 32 + lg * 8);
        acc[0][n] = MFMA16(a[0][ks], b, acc[0][n]);
        acc[1][n] = MFMA16(a[1][ks], b, acc[1][n]);
      }
#pragma unroll
    for (int n = 0; n < 8; ++n) {
      float bv = bpl[n * 16 + lr];
#pragma unroll
      for (int m = 0; m < 2; ++m)
#pragma unroll
        for (int r = 0; r < 4; ++r)
          Lw[w][m * 16 + 4 * lg + r][n * 16 + lr] = __float2bfloat16(acc[m][n][r] + bv);
    }
    if (stage == 0) {
#pragma unroll
      for (int c = 0; c < 8; ++c) {
        int row_l = c * 4 + lg;
        short8v v = *reinterpret_cast<const short8v*>(&Lw[w][row_l][lr * 8]);
        *reinterpret_cast<short8v*>(Yq + (R0 + row_l) * 128 + lr * 8) = v;
      }
    }
  }
  __syncthreads();   // hw staged (waves 0,1) + all Lw complete
  // ---- heads on y_l2 tile: lane = (row rr, half hh) ----
  {
    const int rr = lane >> 1, hh = lane & 1;
    float d0 = 0.f, d1 = 0.f, d2 = 0.f;
#pragma unroll
    for (int j = 0; j < 8; ++j) {
      short8v v8 = *reinterpret_cast<const short8v*>(&Lw[w][rr][hh * 64 + j * 8]);
      const bh* vv = reinterpret_cast<const bh*>(&v8);
#pragma unroll
      for (int k = 0; k < 8; ++k) {
        float f = __bfloat162float(vv[k]);
        int c = hh * 64 + j * 8 + k;
        d0 = fmaf(f, hw[0][c], d0);
        d1 = fmaf(f, hw[1][c], d1);
        d2 = fmaf(f, hw[2][c], d2);
      }
    }
    d0 += __shfl_xor(d0, 1, 64);
    d1 += __shfl_xor(d1, 1, 64);
    d2 += __shfl_xor(d2, 1, 64);
    if (hh == 0) {
      long row = R0 + rr;
      d0 += rb[0]; d1 += cb[0]; d2 += cb[1];
      float mx = fmaxf(d1, d2);
      float e1 = __expf(d1 - mx), e2 = __expf(d2 - mx);
      float inv = 1.f / (e1 + e2);
      out[off_reg + row] = d0;
      out[off_cla + row * 2] = e1 * inv;
      out[off_cla + row * 2 + 1] = e2 * inv;
    }
  }
}

// ---------------------------------------------------------------------------
// Fused final: fused = X·Was^T + b + Prev (Prev added in f32 at heads read);
// heads directly, no fused buffer materialized.
// ---------------------------------------------------------------------------
__global__ __launch_bounds__(256) void sf_fin(const bh* __restrict__ X,
                                              const bh* __restrict__ Was, const float* __restrict__ bo,
                                              const bh* __restrict__ Prev,
                                              const float* __restrict__ rw, const float* __restrict__ rb,
                                              const float* __restrict__ cw, const float* __restrict__ cb,
                                              float* __restrict__ out, long off_reg, long off_cla) {
  __shared__ bh Lw[4][32][140];
  __shared__ float hw[3][128];
  const int t = threadIdx.x, lane = t & 63, w = t >> 6;
  const int lr = lane & 15, lg = lane >> 4;
  const long R0 = (long)blockIdx.x * 128 + w * 32;
  const f32x4 z4 = {0.f, 0.f, 0.f, 0.f};
  if (t < 128) { hw[0][t] = rw[t]; hw[1][t] = cw[t]; hw[2][t] = cw[128 + t]; }
  {
    short8v a[2][4];
#pragma unroll
    for (int ks = 0; ks < 4; ++ks) {
      a[0][ks] = *reinterpret_cast<const short8v*>(X + (R0 + lr) * 128 + ks * 32 + lg * 8);
      a[1][ks] = *reinterpret_cast<const short8v*>(X + (R0 + 16 + lr) * 128 + ks * 32 + lg * 8);
    }
    f32x4 acc[2][8];
#pragma unroll
    for (int m = 0; m < 2; ++m)
#pragma unroll
      for (int n = 0; n < 8; ++n) acc[m][n] = z4;
#pragma unroll
    for (int ks = 0; ks < 4; ++ks)
#pragma unroll
      for (int n = 0; n < 8; ++n) {
        short8v b = *reinterpret_cast<const short8v*>(Was + (long)(n * 16 + lr) * 128 + ks * 32 + lg * 8);
        acc[0][n] = MFMA16(a[0][ks], b, acc[0][n]);
        acc[1][n] = MFMA16(a[1][ks], b, acc[1][n]);
      }
#pragma unroll
    for (int n = 0; n < 8; ++n) {
      float bv = bo[n * 16 + lr];
#pragma unroll
      for (int m = 0; m < 2; ++m)
#pragma unroll
        for (int r = 0; r < 4; ++r)
          Lw[w][m * 16 + 4 * lg + r][n * 16 + lr] = __float2bfloat16(acc[m][n][r] + bv);
    }
  }
  __syncthreads();
  {
    const int rr = lane >> 1, hh = lane & 1;
    float d0 = 0.f, d1 = 0.f, d2 = 0.f;
#pragma unroll
    for (int j = 0; j < 8; ++j) {
      short8v v8 = *reinterpret_cast<const short8v*>(&Lw[w][rr][hh * 64 + j * 8]);
      short8v p8 = *reinterpret_cast<const short8v*>(Prev + (R0 + rr) * 128 + hh * 64 + j * 8);
      const bh* vv = reinterpret_cast<const bh*>(&v8);
      const bh* pp = reinterpret_cast<const bh*>(&p8);
#pragma unroll
      for (int k = 0; k < 8; ++k) {
        float f = __bfloat162float(vv[k]) + __bfloat162float(pp[k]);
        int c = hh * 64 + j * 8 + k;
        d0 = fmaf(f, hw[0][c], d0);
        d1 = fmaf(f, hw[1][c], d1);
        d2 = fmaf(f, hw[2][c], d2);
      }
    }
    d0 += __shfl_xor(d0, 1, 64);
    d1 += __shfl_xor(d1, 1, 64);
    d2 += __shfl_xor(d2, 1, 64);
    if (hh == 0) {
      long row = R0 + rr;
      d0 += rb[0]; d1 += cb[0]; d2 += cb[1];
      float mx = fmaxf(d1, d2);
      float e1 = __expf(d1 - mx), e2 = __expf(d2 - mx);
      float inv = 1.f / (e1 + e2);
      out[off_reg + row] = d0;
      out[off_cla + row * 2] = e1 * inv;
      out[off_cla + row * 2 + 1] = e2 * inv;
    }
  }
}

// ---------------------------------------------------------------------------
extern "C" void kernel_launch(void* const* d_in, const int* in_sizes, int n_in,
                              void* d_out, int out_size, void* d_ws, size_t ws_size,
                              hipStream_t stream) {
  (void)in_sizes; (void)n_in; (void)out_size; (void)ws_size;
  const float* x       = (const float*)d_in[0];
  const float* ta_w_in = (const float*)d_in[2];
  const float* ta_b_in = (const float*)d_in[3];
  const float* ta_w_o  = (const float*)d_in[4];
  const float* ta_b_o  = (const float*)d_in[5];
  const float* conv_w  = (const float*)d_in[6];
  const float* conv_b  = (const float*)d_in[7];
  const float* pl_w    = (const float*)d_in[8];
  const float* pl_b    = (const float*)d_in[9];
  const float* ph_w    = (const float*)d_in[10];
  const float* ph_b    = (const float*)d_in[11];
  const float* as_w_in = (const float*)d_in[12];
  const float* as_b_in = (const float*)d_in[13];
  const float* as_w_o  = (const float*)d_in[14];
  const float* as_b_o  = (const float*)d_in[15];
  const float* ac_w_in = (const float*)d_in[16];
  const float* ac_b_in = (const float*)d_in[17];
  const float* ac_w_o  = (const float*)d_in[18];
  const float* ac_b_o  = (const float*)d_in[19];
  const float* rl_w    = (const float*)d_in[20];
  const float* rl_b    = (const float*)d_in[21];
  const float* cl_w    = (const float*)d_in[22];
  const float* cl_b    = (const float*)d_in[23];
  const float* rf_w    = (const float*)d_in[24];
  const float* rf_b    = (const float*)d_in[25];
  const float* cf_w    = (const float*)d_in[26];
  const float* cf_b    = (const float*)d_in[27];
  float* out = (float*)d_out;

  bh* S0 = (bh*)d_ws;
  bh* S1 = S0 + SF_ELEMS;
  bh* S2 = S1 + SF_ELEMS;
  bh* S3 = S2 + SF_ELEMS;
  bh* S4 = S3 + SF_ELEMS;
  bh* A  = S4 + SF_ELEMS;             // bf16 arena (278528)
  float* PE = (float*)(A + 278528);   // 32768 f32

  dim3 blk(256);
  const int GZ = (int)(SF_ELEMS / 256);
  const int GL = 1024;                // 131072 / 128

  sf_wcvt<<<1088, blk, 0, stream>>>(ta_w_in, ta_w_o, pl_w, ph_w, ac_w_in, ac_w_o,
                                    as_w_in, as_w_o, conv_w, A);
  sf_pe<<<128, blk, 0, stream>>>(PE);

  // ---- encoder ----
  sf_buildzx<<<GZ, blk, 0, stream>>>(x, PE, S0, S3);                           // S0 = z, S3 = xh
  sf_attnp<<<2048, blk, 0, stream>>>(S0, S0, A, ta_b_in, S1);                  // S1 = enc attn
  sf_encdec<<<GL, blk, 0, stream>>>(S1, A + 49152, ta_b_o, A + 65536, pl_b,
                                    rl_w, rl_b, cl_w, cl_b, S2, out,
                                    393216L, 524288L);                         // S2 = q_l + lreg/lcla
  sf_convm<<<1024, blk, 0, stream>>>(S3, A + 229376, conv_b, S4);              // S4 = y_h
  sf_lin<<<GL, blk, 0, stream>>>(S4, A + 81920, ph_b, S0);                     // S0 = k_h

  // ---- cross attention (q = q_l, k/v = k_h) ----
  sf_attnp<<<2048, blk, 0, stream>>>(S2, S0, A + 98304, ac_b_in, S3);          // S3 = cross attn
  sf_lin<<<GL, blk, 0, stream>>>(S3, A + 147456, ac_b_o, S4);                  // S4 = a_cross

  // ---- self attention (q/k/v = q_l) ----
  sf_attnp<<<2048, blk, 0, stream>>>(S2, S2, A + 163840, as_b_in, S1);         // S1 = self attn
  sf_fin<<<GL, blk, 0, stream>>>(S1, A + 212992, as_b_o, S4,
                                 rf_w, rf_b, cf_w, cf_b, out, 0L, 131072L);    // reg/cla
}